// Round 2
// baseline (665.351 us; speedup 1.0000x reference)
//
#include <hip/hip_runtime.h>
#include <hip/hip_bf16.h>
#include <math.h>

#define NSEQ 2048
#define NH 8
#define DH 64
#define KP 32
#define DM 512
#define NB 2
#define MROWS (NB * NSEQ)   // 4096

static __constant__ float RZF[KP] = {
    14.134725142f, 21.022039639f, 25.01085758f,  30.424876126f, 32.935061588f,
    37.586178159f, 40.918719012f, 43.327073281f, 48.005150881f, 49.773832478f,
    52.970321478f, 56.446247697f, 59.347044003f, 60.831778525f, 65.112544048f,
    67.079810529f, 69.546401711f, 72.067157674f, 75.704690699f, 77.144840069f,
    79.33737502f,  82.910380854f, 84.735492981f, 87.425274613f, 88.809111208f,
    92.491899271f, 94.651344041f, 95.870634228f, 98.831194218f, 101.317851006f,
    103.72553804f, 105.446623052f};

// ---------------------------------------------------------------------------
// K1: per-(h,t) tables: cos/sin[h][t][32] and biasK[h][t] = (exp(ll_h)/32)*S[h][t]
// S[h][t] = sum_p floor(theta/TAU); theta monotone in t => causal |diff| telescopes,
// row-constant part cancels in softmax, leaving per-key bias +lam/32*S[h][j].
// ---------------------------------------------------------------------------
__global__ __launch_bounds__(256) void k_tables(
    const float* __restrict__ ls, const float* __restrict__ ll,
    float* __restrict__ cosT, float* __restrict__ sinT, float* __restrict__ biasK)
{
    int idx = blockIdx.x * 256 + threadIdx.x;       // h*NSEQ + t
    if (idx >= NH * NSEQ) return;
    int h = idx >> 11;
    int t = idx & (NSEQ - 1);
    float scale = expf(ls[h]);
    float lam32 = expf(ll[h]) * (1.0f / 32.0f);
    float tau = log1pf((float)t);
    const float TAUF = 6.2831853071795864769f;
    float ssum = 0.0f;
    float* cp = cosT + (size_t)idx * KP;
    float* sp = sinT + (size_t)idx * KP;
#pragma unroll
    for (int p = 0; p < KP; ++p) {
        float g  = RZF[p] / RZF[0];
        float th = (tau * g) * scale;
        cp[p] = cosf(th);
        sp[p] = sinf(th);
        ssum += floorf(th / TAUF);
    }
    biasK[idx] = lam32 * ssum;
}

// ---------------------------------------------------------------------------
// K2: qkv GEMM  x(4096x512) @ w_qkv(512x1536), fused rotation epilogue.
// Writes q_rot/k_rot/v as [b][h][n][dh] fp32.
// ---------------------------------------------------------------------------
__global__ __launch_bounds__(256) void k_gemm_qkv(
    const float* __restrict__ x, const float* __restrict__ w,
    const float* __restrict__ cosT, const float* __restrict__ sinT,
    float* __restrict__ qrot, float* __restrict__ krot, float* __restrict__ vout)
{
    __shared__ float As[16][65];   // [k][m], padded
    __shared__ float Bs[16][64];   // [k][n]
    int bm = blockIdx.y << 6;
    int bn = blockIdx.x << 6;
    int tid = threadIdx.x;
    int tx = tid & 15, ty = tid >> 4;
    float acc[4][4];
#pragma unroll
    for (int i = 0; i < 4; ++i)
#pragma unroll
        for (int j = 0; j < 4; ++j) acc[i][j] = 0.0f;

    for (int k0 = 0; k0 < DM; k0 += 16) {
        int ar = tid >> 2, ac = (tid & 3) << 2;
        float4 av = *(const float4*)(x + (size_t)(bm + ar) * DM + k0 + ac);
        As[ac + 0][ar] = av.x; As[ac + 1][ar] = av.y;
        As[ac + 2][ar] = av.z; As[ac + 3][ar] = av.w;
        int br = tid >> 4, bc = (tid & 15) << 2;
        *(float4*)&Bs[br][bc] = *(const float4*)(w + (size_t)(k0 + br) * (3 * DM) + bn + bc);
        __syncthreads();
#pragma unroll
        for (int k = 0; k < 16; ++k) {
            float a0 = As[k][(ty << 2) + 0], a1 = As[k][(ty << 2) + 1];
            float a2 = As[k][(ty << 2) + 2], a3 = As[k][(ty << 2) + 3];
            float b0 = Bs[k][(tx << 2) + 0], b1 = Bs[k][(tx << 2) + 1];
            float b2 = Bs[k][(tx << 2) + 2], b3 = Bs[k][(tx << 2) + 3];
            acc[0][0] = fmaf(a0, b0, acc[0][0]); acc[0][1] = fmaf(a0, b1, acc[0][1]);
            acc[0][2] = fmaf(a0, b2, acc[0][2]); acc[0][3] = fmaf(a0, b3, acc[0][3]);
            acc[1][0] = fmaf(a1, b0, acc[1][0]); acc[1][1] = fmaf(a1, b1, acc[1][1]);
            acc[1][2] = fmaf(a1, b2, acc[1][2]); acc[1][3] = fmaf(a1, b3, acc[1][3]);
            acc[2][0] = fmaf(a2, b0, acc[2][0]); acc[2][1] = fmaf(a2, b1, acc[2][1]);
            acc[2][2] = fmaf(a2, b2, acc[2][2]); acc[2][3] = fmaf(a2, b3, acc[2][3]);
            acc[3][0] = fmaf(a3, b0, acc[3][0]); acc[3][1] = fmaf(a3, b1, acc[3][1]);
            acc[3][2] = fmaf(a3, b2, acc[3][2]); acc[3][3] = fmaf(a3, b3, acc[3][3]);
        }
        __syncthreads();
    }
    // epilogue: col = sec*512 + h*64 + dh ; 4-col group never straddles sections
    int cbase = bn + (tx << 2);
    int sec   = cbase >> 9;          // 0=q 1=k 2=v
    int dmod  = cbase & 511;
    int h     = dmod >> 6;
    int dh    = dmod & 63;           // multiple of 4
    int p0    = dh >> 1;             // pair index (even)
#pragma unroll
    for (int i = 0; i < 4; ++i) {
        int m = bm + (ty << 2) + i;
        int b = m >> 11, t = m & (NSEQ - 1);
        size_t obase = ((size_t)(b * NH + h) * NSEQ + t) * DH + dh;
        if (sec == 2) {
            *(float4*)(vout + obase) = make_float4(acc[i][0], acc[i][1], acc[i][2], acc[i][3]);
        } else {
            const float* cp = cosT + ((size_t)h * NSEQ + t) * KP + p0;
            const float* sp = sinT + ((size_t)h * NSEQ + t) * KP + p0;
            float c0 = cp[0], s0 = sp[0], c1 = cp[1], s1 = sp[1];
            float r0 = acc[i][0] * c0 - acc[i][1] * s0;
            float r1 = acc[i][0] * s0 + acc[i][1] * c0;
            float r2 = acc[i][2] * c1 - acc[i][3] * s1;
            float r3 = acc[i][2] * s1 + acc[i][3] * c1;
            float* dst = (sec == 0 ? qrot : krot);
            *(float4*)(dst + obase) = make_float4(r0, r1, r2, r3);
        }
    }
}

// ---------------------------------------------------------------------------
// K3: flash attention per (b,h, 64-query tile). 256 thr = 4 waves.
// Thread (ql = tid&63, dseg = tid>>6): Q row ql in registers; computes scores
// for keys [dseg*16, dseg*16+16) of each 64-key tile; accumulates V columns
// [dseg*16, +16). Online softmax state (m,l) kept redundantly per thread.
// ---------------------------------------------------------------------------
__global__ __launch_bounds__(256) void k_attn(
    const float* __restrict__ qr, const float* __restrict__ kr,
    const float* __restrict__ vr, const float* __restrict__ biasK,
    float* __restrict__ ao)
{
    __shared__ float Ks[64][64];    // [j][d] (reads are wave-broadcast)
    __shared__ float Vs[64][64];
    __shared__ float SsT[64][64];   // [j][q] (lane-q reads/writes conflict-free)
    __shared__ float Bk[64];
    int bh = blockIdx.y;            // b*8 + h
    int b = bh >> 3, h = bh & 7;
    int q0 = blockIdx.x << 6;
    int tid = threadIdx.x;
    int ql = tid & 63;
    int dseg = tid >> 6;
    int d0 = dseg << 4;
    int qg = q0 + ql;
    const float* qb = qr + (size_t)bh * NSEQ * DH;
    const float* kb = kr + (size_t)bh * NSEQ * DH;
    const float* vb = vr + (size_t)bh * NSEQ * DH;
    const float* bkrow = biasK + (size_t)h * NSEQ;

    float qreg[64];
#pragma unroll
    for (int u = 0; u < 16; ++u) {
        float4 t4 = *(const float4*)(qb + (size_t)qg * DH + (u << 2));
        qreg[(u << 2) + 0] = t4.x; qreg[(u << 2) + 1] = t4.y;
        qreg[(u << 2) + 2] = t4.z; qreg[(u << 2) + 3] = t4.w;
    }
    float acc[16];
#pragma unroll
    for (int i = 0; i < 16; ++i) acc[i] = 0.0f;
    float mr = -3.0e38f, lr = 0.0f;

    int ntiles = blockIdx.x + 1;    // causal: key tiles with j0 <= q0
    for (int tile = 0; tile < ntiles; ++tile) {
        int j0 = tile << 6;
        __syncthreads();            // protect LDS from previous iteration's readers
        for (int idx = tid; idx < 64 * 16; idx += 256) {
            int r = idx >> 4, c4 = (idx & 15) << 2;
            *(float4*)&Ks[r][c4] = *(const float4*)(kb + (size_t)(j0 + r) * DH + c4);
            *(float4*)&Vs[r][c4] = *(const float4*)(vb + (size_t)(j0 + r) * DH + c4);
        }
        if (tid < 64) Bk[tid] = bkrow[j0 + tid];
        __syncthreads();

        float s[16];
#pragma unroll
        for (int jj = 0; jj < 16; ++jj) s[jj] = 0.0f;
#pragma unroll
        for (int d4 = 0; d4 < 64; d4 += 4) {
#pragma unroll
            for (int jj = 0; jj < 16; ++jj) {
                float4 kv = *(const float4*)&Ks[d0 + jj][d4];
                s[jj] = fmaf(qreg[d4 + 0], kv.x, s[jj]);
                s[jj] = fmaf(qreg[d4 + 1], kv.y, s[jj]);
                s[jj] = fmaf(qreg[d4 + 2], kv.z, s[jj]);
                s[jj] = fmaf(qreg[d4 + 3], kv.w, s[jj]);
            }
        }
#pragma unroll
        for (int jj = 0; jj < 16; ++jj) {
            int jg = j0 + d0 + jj;
            float val = s[jj] * 0.125f + Bk[d0 + jj];
            SsT[d0 + jj][ql] = (jg <= qg) ? val : -__builtin_inff();
        }
        __syncthreads();

        float mt = mr;
        for (int j = 0; j < 64; ++j) mt = fmaxf(mt, SsT[j][ql]);
        float corr = expf(mr - mt);
        lr *= corr;
#pragma unroll
        for (int i = 0; i < 16; ++i) acc[i] *= corr;
        mr = mt;
        for (int j = 0; j < 64; ++j) {
            float p = expf(SsT[j][ql] - mr);   // masked entries: exp(-inf)=0
            lr += p;
            float4 v0 = *(const float4*)&Vs[j][d0 + 0];
            float4 v1 = *(const float4*)&Vs[j][d0 + 4];
            float4 v2 = *(const float4*)&Vs[j][d0 + 8];
            float4 v3 = *(const float4*)&Vs[j][d0 + 12];
            acc[0]  = fmaf(p, v0.x, acc[0]);  acc[1]  = fmaf(p, v0.y, acc[1]);
            acc[2]  = fmaf(p, v0.z, acc[2]);  acc[3]  = fmaf(p, v0.w, acc[3]);
            acc[4]  = fmaf(p, v1.x, acc[4]);  acc[5]  = fmaf(p, v1.y, acc[5]);
            acc[6]  = fmaf(p, v1.z, acc[6]);  acc[7]  = fmaf(p, v1.w, acc[7]);
            acc[8]  = fmaf(p, v2.x, acc[8]);  acc[9]  = fmaf(p, v2.y, acc[9]);
            acc[10] = fmaf(p, v2.z, acc[10]); acc[11] = fmaf(p, v2.w, acc[11]);
            acc[12] = fmaf(p, v3.x, acc[12]); acc[13] = fmaf(p, v3.y, acc[13]);
            acc[14] = fmaf(p, v3.z, acc[14]); acc[15] = fmaf(p, v3.w, acc[15]);
        }
    }
    float inv = 1.0f / lr;
    float* op = ao + ((size_t)b * NSEQ + qg) * DM + h * DH + d0;
    *(float4*)(op + 0)  = make_float4(acc[0] * inv,  acc[1] * inv,  acc[2] * inv,  acc[3] * inv);
    *(float4*)(op + 4)  = make_float4(acc[4] * inv,  acc[5] * inv,  acc[6] * inv,  acc[7] * inv);
    *(float4*)(op + 8)  = make_float4(acc[8] * inv,  acc[9] * inv,  acc[10] * inv, acc[11] * inv);
    *(float4*)(op + 12) = make_float4(acc[12] * inv, acc[13] * inv, acc[14] * inv, acc[15] * inv);
}

// ---------------------------------------------------------------------------
// K4: output GEMM  ao(4096x512) @ w_o(512x512) -> f32 out (reference output is f32)
// ---------------------------------------------------------------------------
__global__ __launch_bounds__(256) void k_gemm_out(
    const float* __restrict__ a, const float* __restrict__ w,
    float* __restrict__ out)
{
    __shared__ float As[16][65];
    __shared__ float Bs[16][64];
    int bm = blockIdx.y << 6;
    int bn = blockIdx.x << 6;
    int tid = threadIdx.x;
    int tx = tid & 15, ty = tid >> 4;
    float acc[4][4];
#pragma unroll
    for (int i = 0; i < 4; ++i)
#pragma unroll
        for (int j = 0; j < 4; ++j) acc[i][j] = 0.0f;

    for (int k0 = 0; k0 < DM; k0 += 16) {
        int ar = tid >> 2, ac = (tid & 3) << 2;
        float4 av = *(const float4*)(a + (size_t)(bm + ar) * DM + k0 + ac);
        As[ac + 0][ar] = av.x; As[ac + 1][ar] = av.y;
        As[ac + 2][ar] = av.z; As[ac + 3][ar] = av.w;
        int br = tid >> 4, bc = (tid & 15) << 2;
        *(float4*)&Bs[br][bc] = *(const float4*)(w + (size_t)(k0 + br) * DM + bn + bc);
        __syncthreads();
#pragma unroll
        for (int k = 0; k < 16; ++k) {
            float a0 = As[k][(ty << 2) + 0], a1 = As[k][(ty << 2) + 1];
            float a2 = As[k][(ty << 2) + 2], a3 = As[k][(ty << 2) + 3];
            float b0 = Bs[k][(tx << 2) + 0], b1 = Bs[k][(tx << 2) + 1];
            float b2 = Bs[k][(tx << 2) + 2], b3 = Bs[k][(tx << 2) + 3];
            acc[0][0] = fmaf(a0, b0, acc[0][0]); acc[0][1] = fmaf(a0, b1, acc[0][1]);
            acc[0][2] = fmaf(a0, b2, acc[0][2]); acc[0][3] = fmaf(a0, b3, acc[0][3]);
            acc[1][0] = fmaf(a1, b0, acc[1][0]); acc[1][1] = fmaf(a1, b1, acc[1][1]);
            acc[1][2] = fmaf(a1, b2, acc[1][2]); acc[1][3] = fmaf(a1, b3, acc[1][3]);
            acc[2][0] = fmaf(a2, b0, acc[2][0]); acc[2][1] = fmaf(a2, b1, acc[2][1]);
            acc[2][2] = fmaf(a2, b2, acc[2][2]); acc[2][3] = fmaf(a2, b3, acc[2][3]);
            acc[3][0] = fmaf(a3, b0, acc[3][0]); acc[3][1] = fmaf(a3, b1, acc[3][1]);
            acc[3][2] = fmaf(a3, b2, acc[3][2]); acc[3][3] = fmaf(a3, b3, acc[3][3]);
        }
        __syncthreads();
    }
    int cbase = bn + (tx << 2);
#pragma unroll
    for (int i = 0; i < 4; ++i) {
        int m = bm + (ty << 2) + i;
        *(float4*)(out + (size_t)m * DM + cbase) =
            make_float4(acc[i][0], acc[i][1], acc[i][2], acc[i][3]);
    }
}

// ---------------------------------------------------------------------------
extern "C" void kernel_launch(void* const* d_in, const int* in_sizes, int n_in,
                              void* d_out, int out_size, void* d_ws, size_t ws_size,
                              hipStream_t stream)
{
    const float* x  = (const float*)d_in[0];
    const float* wq = (const float*)d_in[1];
    const float* wo = (const float*)d_in[2];
    const float* ls = (const float*)d_in[3];
    const float* ll = (const float*)d_in[4];
    float* out = (float*)d_out;

    char* ws = (char*)d_ws;
    size_t off = 0;
    float* cosT  = (float*)(ws + off); off += (size_t)NH * NSEQ * KP * 4;       // 2 MB
    float* sinT  = (float*)(ws + off); off += (size_t)NH * NSEQ * KP * 4;       // 2 MB
    float* biasK = (float*)(ws + off); off += (size_t)NH * NSEQ * 4;            // 64 KB
    float* qrot  = (float*)(ws + off); off += (size_t)NB * NH * NSEQ * DH * 4;  // 8 MB
    float* krot  = (float*)(ws + off); off += (size_t)NB * NH * NSEQ * DH * 4;  // 8 MB
    float* vbuf  = (float*)(ws + off); off += (size_t)NB * NH * NSEQ * DH * 4;  // 8 MB
    float* ao    = (float*)(ws + off); off += (size_t)MROWS * DM * 4;           // 8 MB

    k_tables<<<(NH * NSEQ + 255) / 256, 256, 0, stream>>>(ls, ll, cosT, sinT, biasK);
    k_gemm_qkv<<<dim3((3 * DM) / 64, MROWS / 64), 256, 0, stream>>>(
        x, wq, cosT, sinT, qrot, krot, vbuf);
    k_attn<<<dim3(NSEQ / 64, NB * NH), 256, 0, stream>>>(qrot, krot, vbuf, biasK, ao);
    k_gemm_out<<<dim3(DM / 64, MROWS / 64), 256, 0, stream>>>(ao, wo, out);
}

// Round 3
// 206.047 us; speedup vs baseline: 3.2291x; 3.2291x over previous
//
#include <hip/hip_runtime.h>
#include <hip/hip_bf16.h>
#include <math.h>

#define NSEQ 2048
#define NH 8
#define DH 64
#define KP 32
#define DM 512
#define NB 2
#define MROWS (NB * NSEQ)   // 4096

typedef short bf16x8 __attribute__((ext_vector_type(8)));
typedef float f32x4  __attribute__((ext_vector_type(4)));

static __constant__ float RZF[KP] = {
    14.134725142f, 21.022039639f, 25.01085758f,  30.424876126f, 32.935061588f,
    37.586178159f, 40.918719012f, 43.327073281f, 48.005150881f, 49.773832478f,
    52.970321478f, 56.446247697f, 59.347044003f, 60.831778525f, 65.112544048f,
    67.079810529f, 69.546401711f, 72.067157674f, 75.704690699f, 77.144840069f,
    79.33737502f,  82.910380854f, 84.735492981f, 87.425274613f, 88.809111208f,
    92.491899271f, 94.651344041f, 95.870634228f, 98.831194218f, 101.317851006f,
    103.72553804f, 105.446623052f};

static __device__ __forceinline__ unsigned short f2bf(float f) {
    unsigned int u = __float_as_uint(f);
    unsigned int r = (u + 0x7FFFu + ((u >> 16) & 1u)) >> 16;   // RNE
    return (unsigned short)r;
}

// ---------------------------------------------------------------------------
// K1: per-(h,t) tables: cos/sin[h][t][32], biasK[h][t] = (exp(ll_h)/32)*S[h][t]
// theta monotone in t => causal |sheet_i-sheet_j| telescopes to S_i - S_j;
// the row-constant S_i part cancels in softmax -> per-KEY bias only.
// ---------------------------------------------------------------------------
__global__ __launch_bounds__(256) void k_tables(
    const float* __restrict__ ls, const float* __restrict__ ll,
    float* __restrict__ cosT, float* __restrict__ sinT, float* __restrict__ biasK)
{
    int idx = blockIdx.x * 256 + threadIdx.x;       // h*NSEQ + t
    if (idx >= NH * NSEQ) return;
    int h = idx >> 11;
    int t = idx & (NSEQ - 1);
    float scale = expf(ls[h]);
    float lam32 = expf(ll[h]) * (1.0f / 32.0f);
    float tau = log1pf((float)t);
    const float TAUF = 6.2831853071795864769f;
    float ssum = 0.0f;
    float* cp = cosT + (size_t)idx * KP;
    float* sp = sinT + (size_t)idx * KP;
#pragma unroll
    for (int p = 0; p < KP; ++p) {
        float g  = RZF[p] / RZF[0];
        float th = (tau * g) * scale;
        cp[p] = cosf(th);
        sp[p] = sinf(th);
        ssum += floorf(th / TAUF);
    }
    biasK[idx] = lam32 * ssum;
}

// ---------------------------------------------------------------------------
// K2: qkv GEMM  x(4096x512) @ w_qkv(512x1536) in fp32, fused rotation epilogue,
// outputs bf16 q_rot/k_rot/v in [b][h][n][dh] layout.
// ---------------------------------------------------------------------------
__global__ __launch_bounds__(256) void k_gemm_qkv(
    const float* __restrict__ x, const float* __restrict__ w,
    const float* __restrict__ cosT, const float* __restrict__ sinT,
    __hip_bfloat16* __restrict__ qrot, __hip_bfloat16* __restrict__ krot,
    __hip_bfloat16* __restrict__ vout)
{
    __shared__ float As[16][65];   // [k][m], padded
    __shared__ float Bs[16][64];   // [k][n]
    int bm = blockIdx.y << 6;
    int bn = blockIdx.x << 6;
    int tid = threadIdx.x;
    int tx = tid & 15, ty = tid >> 4;
    float acc[4][4];
#pragma unroll
    for (int i = 0; i < 4; ++i)
#pragma unroll
        for (int j = 0; j < 4; ++j) acc[i][j] = 0.0f;

    for (int k0 = 0; k0 < DM; k0 += 16) {
        int ar = tid >> 2, ac = (tid & 3) << 2;
        float4 av = *(const float4*)(x + (size_t)(bm + ar) * DM + k0 + ac);
        As[ac + 0][ar] = av.x; As[ac + 1][ar] = av.y;
        As[ac + 2][ar] = av.z; As[ac + 3][ar] = av.w;
        int br = tid >> 4, bc = (tid & 15) << 2;
        *(float4*)&Bs[br][bc] = *(const float4*)(w + (size_t)(k0 + br) * (3 * DM) + bn + bc);
        __syncthreads();
#pragma unroll
        for (int k = 0; k < 16; ++k) {
            float a0 = As[k][(ty << 2) + 0], a1 = As[k][(ty << 2) + 1];
            float a2 = As[k][(ty << 2) + 2], a3 = As[k][(ty << 2) + 3];
            float b0 = Bs[k][(tx << 2) + 0], b1 = Bs[k][(tx << 2) + 1];
            float b2 = Bs[k][(tx << 2) + 2], b3 = Bs[k][(tx << 2) + 3];
            acc[0][0] = fmaf(a0, b0, acc[0][0]); acc[0][1] = fmaf(a0, b1, acc[0][1]);
            acc[0][2] = fmaf(a0, b2, acc[0][2]); acc[0][3] = fmaf(a0, b3, acc[0][3]);
            acc[1][0] = fmaf(a1, b0, acc[1][0]); acc[1][1] = fmaf(a1, b1, acc[1][1]);
            acc[1][2] = fmaf(a1, b2, acc[1][2]); acc[1][3] = fmaf(a1, b3, acc[1][3]);
            acc[2][0] = fmaf(a2, b0, acc[2][0]); acc[2][1] = fmaf(a2, b1, acc[2][1]);
            acc[2][2] = fmaf(a2, b2, acc[2][2]); acc[2][3] = fmaf(a2, b3, acc[2][3]);
            acc[3][0] = fmaf(a3, b0, acc[3][0]); acc[3][1] = fmaf(a3, b1, acc[3][1]);
            acc[3][2] = fmaf(a3, b2, acc[3][2]); acc[3][3] = fmaf(a3, b3, acc[3][3]);
        }
        __syncthreads();
    }
    int cbase = bn + (tx << 2);
    int sec   = cbase >> 9;          // 0=q 1=k 2=v
    int dmod  = cbase & 511;
    int h     = dmod >> 6;
    int dh    = dmod & 63;           // multiple of 4
    int p0    = dh >> 1;             // pair index (even)
#pragma unroll
    for (int i = 0; i < 4; ++i) {
        int m = bm + (ty << 2) + i;
        int b = m >> 11, t = m & (NSEQ - 1);
        size_t obase = ((size_t)(b * NH + h) * NSEQ + t) * DH + dh;
        union { unsigned short s[4]; uint2 u; } pk;
        if (sec == 2) {
            pk.s[0] = f2bf(acc[i][0]); pk.s[1] = f2bf(acc[i][1]);
            pk.s[2] = f2bf(acc[i][2]); pk.s[3] = f2bf(acc[i][3]);
            *(uint2*)(vout + obase) = pk.u;
        } else {
            const float* cp = cosT + ((size_t)h * NSEQ + t) * KP + p0;
            const float* sp = sinT + ((size_t)h * NSEQ + t) * KP + p0;
            float c0 = cp[0], s0 = sp[0], c1 = cp[1], s1 = sp[1];
            pk.s[0] = f2bf(acc[i][0] * c0 - acc[i][1] * s0);
            pk.s[1] = f2bf(acc[i][0] * s0 + acc[i][1] * c0);
            pk.s[2] = f2bf(acc[i][2] * c1 - acc[i][3] * s1);
            pk.s[3] = f2bf(acc[i][2] * s1 + acc[i][3] * c1);
            __hip_bfloat16* dst = (sec == 0 ? qrot : krot);
            *(uint2*)(dst + obase) = pk.u;
        }
    }
}

// ---------------------------------------------------------------------------
// K3: MFMA flash attention. Block = 4 waves, 64 q-rows (wave w: rows q0+16w..+15).
// Per 64-key tile: swapped QK^T (S^T = K·Q^T), wave-parallel online softmax
// (row q = lane&15, shfl_xor reduce), P->bf16 in per-wave LDS, PV via MFMA with
// V staged transposed (VT[d][key]) so both operand reads are ds_read_b128.
// ---------------------------------------------------------------------------
__global__ __launch_bounds__(256) void k_attn(
    const __hip_bfloat16* __restrict__ qr, const __hip_bfloat16* __restrict__ kr,
    const __hip_bfloat16* __restrict__ vr, const float* __restrict__ biasK,
    float* __restrict__ ao)
{
    __shared__ __hip_bfloat16 Kl[64 * 64];      // [key][dh], row-swizzled
    __shared__ __hip_bfloat16 Vt[64 * 64];      // [d][key],  row-swizzled
    __shared__ __hip_bfloat16 Pl[4][16 * 64];   // per-wave [q][key], row-swizzled
    __shared__ float Bk[64];

    char* Kb = (char*)Kl;
    char* Vb = (char*)Vt;

    int bh = blockIdx.y;            // b*8 + h
    int b = bh >> 3, h = bh & 7;
    int q0 = blockIdx.x << 6;
    int tid = threadIdx.x;
    int w    = tid >> 6;
    int lane = tid & 63;
    int g    = lane >> 4;           // lane group 0..3
    int c    = lane & 15;           // col-in-fragment
    char* Pb = (char*)(&Pl[w][0]);

    const __hip_bfloat16* qb = qr + (size_t)bh * NSEQ * DH;
    const __hip_bfloat16* kb = kr + (size_t)bh * NSEQ * DH;
    const __hip_bfloat16* vb = vr + (size_t)bh * NSEQ * DH;
    const float* bkrow = biasK + (size_t)h * NSEQ;

    int qg = q0 + (w << 4) + c;     // this lane's softmax row (q = lane&15)

    // Q fragments (B-operand of swapped QK^T): lane reads Q[qg][s*32+g*8 .. +7]
    bf16x8 qf[2];
#pragma unroll
    for (int s = 0; s < 2; ++s)
        qf[s] = *(const bf16x8*)(qb + (size_t)qg * DH + s * 32 + g * 8);

    f32x4 oa[4];                    // O tile accum: lane holds O[q=g*4+r][d=dt*16+c]
#pragma unroll
    for (int dt = 0; dt < 4; ++dt) oa[dt] = (f32x4){0.f, 0.f, 0.f, 0.f};
    float mr = -3.0e38f, lr = 0.0f;

    int ntiles = blockIdx.x + 1;
    for (int tile = 0; tile < ntiles; ++tile) {
        int j0 = tile << 6;
        __syncthreads();            // previous compute done with Kl/Vt
        // ---- stage K (row-major, swizzled) and V (transposed, swizzled) ----
#pragma unroll
        for (int cc = 0; cc < 2; ++cc) {
            int ch = tid * 2 + cc;              // 0..511: r = ch>>3, 16B col = (ch&7)*16
            int r = ch >> 3;
            int coff = (ch & 7) << 4;           // byte offset in 128B row
            uint4 kq = *(const uint4*)(kb + (size_t)(j0 + r) * DH + (coff >> 1));
            *(uint4*)(Kb + ((r * 128 + coff) ^ ((r & 7) << 4))) = kq;
            union { uint4 q; unsigned short s[8]; } vv;
            vv.q = *(const uint4*)(vb + (size_t)(j0 + r) * DH + (coff >> 1));
#pragma unroll
            for (int i = 0; i < 8; ++i) {
                int d = (coff >> 1) + i;
                *(unsigned short*)(Vb + ((d * 128 + r * 2) ^ (((d >> 3) & 7) << 4))) = vv.s[i];
            }
        }
        if (tid < 64) Bk[tid] = bkrow[j0 + tid];
        __syncthreads();

        // ---- S^T = K · Q^T : 4 key-tiles x 2 k-slices ----
        f32x4 st[4];
#pragma unroll
        for (int kt = 0; kt < 4; ++kt) st[kt] = (f32x4){0.f, 0.f, 0.f, 0.f};
#pragma unroll
        for (int s = 0; s < 2; ++s) {
#pragma unroll
            for (int kt = 0; kt < 4; ++kt) {
                int row = kt * 16 + c;
                bf16x8 af = *(const bf16x8*)(Kb + ((row * 128 + s * 64 + g * 16) ^ ((row & 7) << 4)));
                st[kt] = __builtin_amdgcn_mfma_f32_16x16x32_bf16(af, qf[s], st[kt], 0, 0, 0);
            }
        }

        // ---- bias + mask; lane owns S^T[key = kt*16+g*4+r][q = c] ----
        bool lastT = (tile == blockIdx.x);
        float sv[16];
#pragma unroll
        for (int kt = 0; kt < 4; ++kt) {
#pragma unroll
            for (int r4 = 0; r4 < 4; ++r4) {
                int ki = kt * 16 + g * 4 + r4;
                float vl = st[kt][r4] * 0.125f + Bk[ki];
                if (lastT && (j0 + ki > qg)) vl = -3.0e38f;
                sv[kt * 4 + r4] = vl;
            }
        }

        // ---- online softmax (row q = c; values split across 4 lane-groups) ----
        float m16 = sv[0];
#pragma unroll
        for (int i = 1; i < 16; ++i) m16 = fmaxf(m16, sv[i]);
        m16 = fmaxf(m16, __shfl_xor(m16, 16));
        m16 = fmaxf(m16, __shfl_xor(m16, 32));
        float mt = fmaxf(mr, m16);
        float corr = __expf(mr - mt);
        mr = mt;
        float psum = 0.0f;
        unsigned int pw[8];
#pragma unroll
        for (int i = 0; i < 8; ++i) {
            float p0 = __expf(sv[2 * i]     - mt);
            float p1 = __expf(sv[2 * i + 1] - mt);
            psum += p0 + p1;
            pw[i] = (unsigned int)f2bf(p0) | ((unsigned int)f2bf(p1) << 16);
        }
        lr = lr * corr + psum;

        // rescale O accumulators: need corr for q = g*4+r4 (uniform across groups)
        float corrO[4];
#pragma unroll
        for (int r4 = 0; r4 < 4; ++r4) corrO[r4] = __shfl(corr, g * 4 + r4);
#pragma unroll
        for (int dt = 0; dt < 4; ++dt)
#pragma unroll
            for (int r4 = 0; r4 < 4; ++r4) oa[dt][r4] *= corrO[r4];

        // ---- write P (bf16) to per-wave LDS: [q=c][key], 8B per key-tile ----
#pragma unroll
        for (int kt = 0; kt < 4; ++kt) {
            uint2 u2; u2.x = pw[2 * kt]; u2.y = pw[2 * kt + 1];
            *(uint2*)(Pb + ((c * 128 + kt * 32 + g * 8) ^ ((c & 7) << 4))) = u2;
        }
        // wave-local LDS: compiler inserts lgkmcnt between write and read

        // ---- O += P · V  (A = P from LDS, B = V from VT) ----
#pragma unroll
        for (int s = 0; s < 2; ++s) {
            bf16x8 pa = *(const bf16x8*)(Pb + ((c * 128 + s * 64 + g * 16) ^ ((c & 7) << 4)));
#pragma unroll
            for (int dt = 0; dt < 4; ++dt) {
                int d = dt * 16 + c;
                bf16x8 vf = *(const bf16x8*)(Vb + ((d * 128 + s * 64 + g * 16) ^ (((d >> 3) & 7) << 4)));
                oa[dt] = __builtin_amdgcn_mfma_f32_16x16x32_bf16(pa, vf, oa[dt], 0, 0, 0);
            }
        }
    }

    // ---- final: l reduce, scale, store (lane holds O[q=g*4+r4][d=dt*16+c]) ----
    lr += __shfl_xor(lr, 16);
    lr += __shfl_xor(lr, 32);
    float inv = 1.0f / lr;
    float invO[4];
#pragma unroll
    for (int r4 = 0; r4 < 4; ++r4) invO[r4] = __shfl(inv, g * 4 + r4);
#pragma unroll
    for (int dt = 0; dt < 4; ++dt) {
#pragma unroll
        for (int r4 = 0; r4 < 4; ++r4) {
            int row = q0 + (w << 4) + g * 4 + r4;
            ao[((size_t)b * NSEQ + row) * DM + h * DH + dt * 16 + c] = oa[dt][r4] * invO[r4];
        }
    }
}

// ---------------------------------------------------------------------------
// K4: output GEMM  ao(4096x512) @ w_o(512x512) -> f32 out
// ---------------------------------------------------------------------------
__global__ __launch_bounds__(256) void k_gemm_out(
    const float* __restrict__ a, const float* __restrict__ w,
    float* __restrict__ out)
{
    __shared__ float As[16][65];
    __shared__ float Bs[16][64];
    int bm = blockIdx.y << 6;
    int bn = blockIdx.x << 6;
    int tid = threadIdx.x;
    int tx = tid & 15, ty = tid >> 4;
    float acc[4][4];
#pragma unroll
    for (int i = 0; i < 4; ++i)
#pragma unroll
        for (int j = 0; j < 4; ++j) acc[i][j] = 0.0f;

    for (int k0 = 0; k0 < DM; k0 += 16) {
        int ar = tid >> 2, ac = (tid & 3) << 2;
        float4 av = *(const float4*)(a + (size_t)(bm + ar) * DM + k0 + ac);
        As[ac + 0][ar] = av.x; As[ac + 1][ar] = av.y;
        As[ac + 2][ar] = av.z; As[ac + 3][ar] = av.w;
        int br = tid >> 4, bc = (tid & 15) << 2;
        *(float4*)&Bs[br][bc] = *(const float4*)(w + (size_t)(k0 + br) * DM + bn + bc);
        __syncthreads();
#pragma unroll
        for (int k = 0; k < 16; ++k) {
            float a0 = As[k][(ty << 2) + 0], a1 = As[k][(ty << 2) + 1];
            float a2 = As[k][(ty << 2) + 2], a3 = As[k][(ty << 2) + 3];
            float b0 = Bs[k][(tx << 2) + 0], b1 = Bs[k][(tx << 2) + 1];
            float b2 = Bs[k][(tx << 2) + 2], b3 = Bs[k][(tx << 2) + 3];
            acc[0][0] = fmaf(a0, b0, acc[0][0]); acc[0][1] = fmaf(a0, b1, acc[0][1]);
            acc[0][2] = fmaf(a0, b2, acc[0][2]); acc[0][3] = fmaf(a0, b3, acc[0][3]);
            acc[1][0] = fmaf(a1, b0, acc[1][0]); acc[1][1] = fmaf(a1, b1, acc[1][1]);
            acc[1][2] = fmaf(a1, b2, acc[1][2]); acc[1][3] = fmaf(a1, b3, acc[1][3]);
            acc[2][0] = fmaf(a2, b0, acc[2][0]); acc[2][1] = fmaf(a2, b1, acc[2][1]);
            acc[2][2] = fmaf(a2, b2, acc[2][2]); acc[2][3] = fmaf(a2, b3, acc[2][3]);
            acc[3][0] = fmaf(a3, b0, acc[3][0]); acc[3][1] = fmaf(a3, b1, acc[3][1]);
            acc[3][2] = fmaf(a3, b2, acc[3][2]); acc[3][3] = fmaf(a3, b3, acc[3][3]);
        }
        __syncthreads();
    }
    int cbase = bn + (tx << 2);
#pragma unroll
    for (int i = 0; i < 4; ++i) {
        int m = bm + (ty << 2) + i;
        *(float4*)(out + (size_t)m * DM + cbase) =
            make_float4(acc[i][0], acc[i][1], acc[i][2], acc[i][3]);
    }
}

// ---------------------------------------------------------------------------
extern "C" void kernel_launch(void* const* d_in, const int* in_sizes, int n_in,
                              void* d_out, int out_size, void* d_ws, size_t ws_size,
                              hipStream_t stream)
{
    const float* x  = (const float*)d_in[0];
    const float* wq = (const float*)d_in[1];
    const float* wo = (const float*)d_in[2];
    const float* ls = (const float*)d_in[3];
    const float* ll = (const float*)d_in[4];
    float* out = (float*)d_out;

    char* ws = (char*)d_ws;
    size_t off = 0;
    float* cosT  = (float*)(ws + off); off += (size_t)NH * NSEQ * KP * 4;        // 2 MB
    float* sinT  = (float*)(ws + off); off += (size_t)NH * NSEQ * KP * 4;        // 2 MB
    float* biasK = (float*)(ws + off); off += (size_t)NH * NSEQ * 4;             // 64 KB
    __hip_bfloat16* qbf = (__hip_bfloat16*)(ws + off); off += (size_t)MROWS * DM * 2; // 4 MB
    __hip_bfloat16* kbf = (__hip_bfloat16*)(ws + off); off += (size_t)MROWS * DM * 2; // 4 MB
    __hip_bfloat16* vbf = (__hip_bfloat16*)(ws + off); off += (size_t)MROWS * DM * 2; // 4 MB
    float* ao    = (float*)(ws + off); off += (size_t)MROWS * DM * 4;            // 8 MB

    k_tables<<<(NH * NSEQ + 255) / 256, 256, 0, stream>>>(ls, ll, cosT, sinT, biasK);
    k_gemm_qkv<<<dim3((3 * DM) / 64, MROWS / 64), 256, 0, stream>>>(
        x, wq, cosT, sinT, qbf, kbf, vbf);
    k_attn<<<dim3(NSEQ / 64, NB * NH), 256, 0, stream>>>(qbf, kbf, vbf, biasK, ao);
    k_gemm_out<<<dim3(DM / 64, MROWS / 64), 256, 0, stream>>>(ao, wo, out);
}

// Round 4
// 125.439 us; speedup vs baseline: 5.3042x; 1.6426x over previous
//
#include <hip/hip_runtime.h>
#include <hip/hip_bf16.h>
#include <math.h>

#define NSEQ 2048
#define NH 8
#define DH 64
#define KP 32
#define DM 512
#define NB 2
#define MROWS (NB * NSEQ)   // 4096

typedef short bf16x8 __attribute__((ext_vector_type(8)));
typedef float f32x4  __attribute__((ext_vector_type(4)));

static __constant__ float RZF[KP] = {
    14.134725142f, 21.022039639f, 25.01085758f,  30.424876126f, 32.935061588f,
    37.586178159f, 40.918719012f, 43.327073281f, 48.005150881f, 49.773832478f,
    52.970321478f, 56.446247697f, 59.347044003f, 60.831778525f, 65.112544048f,
    67.079810529f, 69.546401711f, 72.067157674f, 75.704690699f, 77.144840069f,
    79.33737502f,  82.910380854f, 84.735492981f, 87.425274613f, 88.809111208f,
    92.491899271f, 94.651344041f, 95.870634228f, 98.831194218f, 101.317851006f,
    103.72553804f, 105.446623052f};

static __device__ __forceinline__ unsigned short f2bf(float f) {
    unsigned int u = __float_as_uint(f);
    unsigned int r = (u + 0x7FFFu + ((u >> 16) & 1u)) >> 16;   // RNE
    return (unsigned short)r;
}

// async global->LDS, 16B per lane; LDS dest = wave-uniform base + lane*16
static __device__ __forceinline__ void gload16(const void* g, void* l) {
    __builtin_amdgcn_global_load_lds(
        (const __attribute__((address_space(1))) void*)g,
        (__attribute__((address_space(3))) void*)l, 16, 0, 0);
}

// ---------------------------------------------------------------------------
// K1: per-(h,t) tables: cos/sin[h][t][32], biasK[h][t] = (exp(ll_h)/32)*S[h][t]
// theta monotone in t => causal |sheet_i-sheet_j| telescopes to S_i - S_j;
// row-constant part cancels in softmax -> per-KEY bias only.
// ---------------------------------------------------------------------------
__global__ __launch_bounds__(256) void k_tables(
    const float* __restrict__ ls, const float* __restrict__ ll,
    float* __restrict__ cosT, float* __restrict__ sinT, float* __restrict__ biasK)
{
    int idx = blockIdx.x * 256 + threadIdx.x;       // h*NSEQ + t
    if (idx >= NH * NSEQ) return;
    int h = idx >> 11;
    int t = idx & (NSEQ - 1);
    float scale = expf(ls[h]);
    float lam32 = expf(ll[h]) * (1.0f / 32.0f);
    float tau = log1pf((float)t);
    const float TAUF = 6.2831853071795864769f;
    float ssum = 0.0f;
    float* cp = cosT + (size_t)idx * KP;
    float* sp = sinT + (size_t)idx * KP;
#pragma unroll
    for (int p = 0; p < KP; ++p) {
        float g  = RZF[p] / RZF[0];
        float th = (tau * g) * scale;
        cp[p] = cosf(th);
        sp[p] = sinf(th);
        ssum += floorf(th / TAUF);
    }
    biasK[idx] = lam32 * ssum;
}

// ---------------------------------------------------------------------------
// K1b: x (f32) -> bf16, same layout. 8 elems/thread.
// ---------------------------------------------------------------------------
__global__ __launch_bounds__(256) void k_cvt_bf16(
    const float* __restrict__ src, unsigned short* __restrict__ dst, int n8)
{
    int i = blockIdx.x * 256 + threadIdx.x;
    if (i >= n8) return;
    float4 a = ((const float4*)src)[2 * i];
    float4 b = ((const float4*)src)[2 * i + 1];
    union { unsigned short s[8]; uint4 u; } pk;
    pk.s[0] = f2bf(a.x); pk.s[1] = f2bf(a.y); pk.s[2] = f2bf(a.z); pk.s[3] = f2bf(a.w);
    pk.s[4] = f2bf(b.x); pk.s[5] = f2bf(b.y); pk.s[6] = f2bf(b.z); pk.s[7] = f2bf(b.w);
    ((uint4*)dst)[i] = pk.u;
}

// ---------------------------------------------------------------------------
// K1c: transpose-convert  src f32 [R][C] -> dst bf16 [C][R]
// ---------------------------------------------------------------------------
__global__ __launch_bounds__(256) void k_transpose_bf16(
    const float* __restrict__ src, unsigned short* __restrict__ dst, int R, int C)
{
    __shared__ float tile[32][33];
    int x0 = blockIdx.x << 5, y0 = blockIdx.y << 5;
    int tx = threadIdx.x & 31, ty = threadIdx.x >> 5;   // ty 0..7
#pragma unroll
    for (int i = 0; i < 4; ++i)
        tile[ty + i * 8][tx] = src[(size_t)(y0 + ty + i * 8) * C + x0 + tx];
    __syncthreads();
#pragma unroll
    for (int i = 0; i < 4; ++i)
        dst[(size_t)(x0 + ty + i * 8) * R + y0 + tx] = f2bf(tile[tx][ty + i * 8]);
}

// ---------------------------------------------------------------------------
// K2: MFMA GEMM  xb(4096x512 bf16) @ wqT^T  (wqT = [1536][512] bf16), fused
// rotation epilogue -> bf16 q_rot/k_rot/v in [b][h][n][dh].
// 128x128 tile, BK=64, 4 waves; global_load_lds(16B) into XOR-swizzled LDS
// via pre-swizzled global source (rule #21); swizzled ds_read_b128 fragments.
// ---------------------------------------------------------------------------
__global__ __launch_bounds__(256) void k_gemm_qkv(
    const unsigned short* __restrict__ xb, const unsigned short* __restrict__ wt,
    const float* __restrict__ cosT, const float* __restrict__ sinT,
    unsigned short* __restrict__ qrot, unsigned short* __restrict__ krot,
    unsigned short* __restrict__ vout)
{
    __shared__ char Asm[128 * 128];   // 128 rows x 128B (64 bf16), swizzled
    __shared__ char Bsm[128 * 128];
    int tid = threadIdx.x;
    int w = tid >> 6, lane = tid & 63, g = lane >> 4, c = lane & 15;
    int wm = w >> 1, wn = w & 1;
    int bm = blockIdx.y << 7, bn = blockIdx.x << 7;
    int rin = lane >> 3;                       // row-in-8-row-chunk
    int csw = ((lane & 7) ^ rin) << 4;         // pre-swizzled source byte-col

    f32x4 acc[4][4];
#pragma unroll
    for (int mi = 0; mi < 4; ++mi)
#pragma unroll
        for (int ni = 0; ni < 4; ++ni) acc[mi][ni] = (f32x4){0.f, 0.f, 0.f, 0.f};

    const char* Ag = (const char*)xb;
    const char* Bg = (const char*)wt;

    for (int k0 = 0; k0 < DM; k0 += 64) {
        __syncthreads();
#pragma unroll
        for (int ch = 0; ch < 4; ++ch) {
            int row = (w * 4 + ch) * 8 + rin;
            gload16(Ag + ((size_t)(bm + row) * DM + k0) * 2 + csw, Asm + (w * 4 + ch) * 1024);
            gload16(Bg + ((size_t)(bn + row) * DM + k0) * 2 + csw, Bsm + (w * 4 + ch) * 1024);
        }
        __syncthreads();
#pragma unroll
        for (int kk = 0; kk < 2; ++kk) {
            bf16x8 af[4], bfr[4];
#pragma unroll
            for (int mi = 0; mi < 4; ++mi) {
                int row = wm * 64 + mi * 16 + c;
                af[mi] = *(const bf16x8*)(Asm + ((row * 128 + kk * 64 + g * 16) ^ ((row & 7) << 4)));
            }
#pragma unroll
            for (int ni = 0; ni < 4; ++ni) {
                int row = wn * 64 + ni * 16 + c;
                bfr[ni] = *(const bf16x8*)(Bsm + ((row * 128 + kk * 64 + g * 16) ^ ((row & 7) << 4)));
            }
#pragma unroll
            for (int mi = 0; mi < 4; ++mi)
#pragma unroll
                for (int ni = 0; ni < 4; ++ni)
                    acc[mi][ni] = __builtin_amdgcn_mfma_f32_16x16x32_bf16(
                        af[mi], bfr[ni], acc[mi][ni], 0, 0, 0);
        }
    }

    // epilogue: lane holds C[m = ..+g*4+r][n = ..+c]; rotation pairs via shfl_xor(1)
    int lane_odd = c & 1;
#pragma unroll
    for (int ni = 0; ni < 4; ++ni) {
        int n = bn + wn * 64 + ni * 16 + c;
        int sec = n >> 9;               // 0=q 1=k 2=v
        int dmod = n & 511;
        int h = dmod >> 6, dh = dmod & 63, p = dh >> 1;
        const float* cb_ = cosT + (size_t)h * NSEQ * KP + p;
        const float* sb_ = sinT + (size_t)h * NSEQ * KP + p;
        unsigned short* dst = (sec == 0) ? qrot : (sec == 1 ? krot : vout);
#pragma unroll
        for (int mi = 0; mi < 4; ++mi) {
#pragma unroll
            for (int r = 0; r < 4; ++r) {
                int m = bm + wm * 64 + mi * 16 + g * 4 + r;
                int b = m >> 11, t = m & (NSEQ - 1);
                float val = acc[mi][ni][r];
                float pv = __shfl_xor(val, 1);
                size_t ob = ((size_t)(b * NH + h) * NSEQ + t) * DH + dh;
                float o;
                if (sec == 2) {
                    o = val;
                } else {
                    float cv = cb_[(size_t)t * KP], sv = sb_[(size_t)t * KP];
                    o = lane_odd ? (pv * sv + val * cv) : (val * cv - pv * sv);
                }
                dst[ob] = f2bf(o);
            }
        }
    }
}

// ---------------------------------------------------------------------------
// K3: MFMA flash attention (unchanged math); output now bf16.
// ---------------------------------------------------------------------------
__global__ __launch_bounds__(256) void k_attn(
    const __hip_bfloat16* __restrict__ qr, const __hip_bfloat16* __restrict__ kr,
    const __hip_bfloat16* __restrict__ vr, const float* __restrict__ biasK,
    unsigned short* __restrict__ ao)
{
    __shared__ __hip_bfloat16 Kl[64 * 64];      // [key][dh], row-swizzled
    __shared__ __hip_bfloat16 Vt[64 * 64];      // [d][key],  row-swizzled
    __shared__ __hip_bfloat16 Pl[4][16 * 64];   // per-wave [q][key], row-swizzled
    __shared__ float Bk[64];

    char* Kb = (char*)Kl;
    char* Vb = (char*)Vt;

    int bh = blockIdx.y;            // b*8 + h
    int b = bh >> 3, h = bh & 7;
    int q0 = blockIdx.x << 6;
    int tid = threadIdx.x;
    int w    = tid >> 6;
    int lane = tid & 63;
    int g    = lane >> 4;
    int c    = lane & 15;
    char* Pb = (char*)(&Pl[w][0]);

    const __hip_bfloat16* qb = qr + (size_t)bh * NSEQ * DH;
    const __hip_bfloat16* kb = kr + (size_t)bh * NSEQ * DH;
    const __hip_bfloat16* vb = vr + (size_t)bh * NSEQ * DH;
    const float* bkrow = biasK + (size_t)h * NSEQ;

    int qg = q0 + (w << 4) + c;

    bf16x8 qf[2];
#pragma unroll
    for (int s = 0; s < 2; ++s)
        qf[s] = *(const bf16x8*)(qb + (size_t)qg * DH + s * 32 + g * 8);

    f32x4 oa[4];
#pragma unroll
    for (int dt = 0; dt < 4; ++dt) oa[dt] = (f32x4){0.f, 0.f, 0.f, 0.f};
    float mr = -3.0e38f, lr = 0.0f;

    int ntiles = blockIdx.x + 1;
    for (int tile = 0; tile < ntiles; ++tile) {
        int j0 = tile << 6;
        __syncthreads();
#pragma unroll
        for (int cc = 0; cc < 2; ++cc) {
            int ch = tid * 2 + cc;
            int r = ch >> 3;
            int coff = (ch & 7) << 4;
            uint4 kq = *(const uint4*)(kb + (size_t)(j0 + r) * DH + (coff >> 1));
            *(uint4*)(Kb + ((r * 128 + coff) ^ ((r & 7) << 4))) = kq;
            union { uint4 q; unsigned short s[8]; } vv;
            vv.q = *(const uint4*)(vb + (size_t)(j0 + r) * DH + (coff >> 1));
#pragma unroll
            for (int i = 0; i < 8; ++i) {
                int d = (coff >> 1) + i;
                *(unsigned short*)(Vb + ((d * 128 + r * 2) ^ (((d >> 3) & 7) << 4))) = vv.s[i];
            }
        }
        if (tid < 64) Bk[tid] = bkrow[j0 + tid];
        __syncthreads();

        f32x4 st[4];
#pragma unroll
        for (int kt = 0; kt < 4; ++kt) st[kt] = (f32x4){0.f, 0.f, 0.f, 0.f};
#pragma unroll
        for (int s = 0; s < 2; ++s) {
#pragma unroll
            for (int kt = 0; kt < 4; ++kt) {
                int row = kt * 16 + c;
                bf16x8 af = *(const bf16x8*)(Kb + ((row * 128 + s * 64 + g * 16) ^ ((row & 7) << 4)));
                st[kt] = __builtin_amdgcn_mfma_f32_16x16x32_bf16(af, qf[s], st[kt], 0, 0, 0);
            }
        }

        bool lastT = (tile == blockIdx.x);
        float sv[16];
#pragma unroll
        for (int kt = 0; kt < 4; ++kt) {
#pragma unroll
            for (int r4 = 0; r4 < 4; ++r4) {
                int ki = kt * 16 + g * 4 + r4;
                float vl = st[kt][r4] * 0.125f + Bk[ki];
                if (lastT && (j0 + ki > qg)) vl = -3.0e38f;
                sv[kt * 4 + r4] = vl;
            }
        }

        float m16 = sv[0];
#pragma unroll
        for (int i = 1; i < 16; ++i) m16 = fmaxf(m16, sv[i]);
        m16 = fmaxf(m16, __shfl_xor(m16, 16));
        m16 = fmaxf(m16, __shfl_xor(m16, 32));
        float mt = fmaxf(mr, m16);
        float corr = __expf(mr - mt);
        mr = mt;
        float psum = 0.0f;
        unsigned int pw[8];
#pragma unroll
        for (int i = 0; i < 8; ++i) {
            float p0 = __expf(sv[2 * i]     - mt);
            float p1 = __expf(sv[2 * i + 1] - mt);
            psum += p0 + p1;
            pw[i] = (unsigned int)f2bf(p0) | ((unsigned int)f2bf(p1) << 16);
        }
        lr = lr * corr + psum;

        float corrO[4];
#pragma unroll
        for (int r4 = 0; r4 < 4; ++r4) corrO[r4] = __shfl(corr, g * 4 + r4);
#pragma unroll
        for (int dt = 0; dt < 4; ++dt)
#pragma unroll
            for (int r4 = 0; r4 < 4; ++r4) oa[dt][r4] *= corrO[r4];

#pragma unroll
        for (int kt = 0; kt < 4; ++kt) {
            uint2 u2; u2.x = pw[2 * kt]; u2.y = pw[2 * kt + 1];
            *(uint2*)(Pb + ((c * 128 + kt * 32 + g * 8) ^ ((c & 7) << 4))) = u2;
        }

#pragma unroll
        for (int s = 0; s < 2; ++s) {
            bf16x8 pa = *(const bf16x8*)(Pb + ((c * 128 + s * 64 + g * 16) ^ ((c & 7) << 4)));
#pragma unroll
            for (int dt = 0; dt < 4; ++dt) {
                int d = dt * 16 + c;
                bf16x8 vf = *(const bf16x8*)(Vb + ((d * 128 + s * 64 + g * 16) ^ (((d >> 3) & 7) << 4)));
                oa[dt] = __builtin_amdgcn_mfma_f32_16x16x32_bf16(pa, vf, oa[dt], 0, 0, 0);
            }
        }
    }

    lr += __shfl_xor(lr, 16);
    lr += __shfl_xor(lr, 32);
    float inv = 1.0f / lr;
    float invO[4];
#pragma unroll
    for (int r4 = 0; r4 < 4; ++r4) invO[r4] = __shfl(inv, g * 4 + r4);
#pragma unroll
    for (int dt = 0; dt < 4; ++dt) {
#pragma unroll
        for (int r4 = 0; r4 < 4; ++r4) {
            int row = q0 + (w << 4) + g * 4 + r4;
            ao[((size_t)b * NSEQ + row) * DM + h * DH + dt * 16 + c] =
                f2bf(oa[dt][r4] * invO[r4]);
        }
    }
}

// ---------------------------------------------------------------------------
// K4: MFMA GEMM  aob(4096x512 bf16) @ woT^T -> f32 out
// ---------------------------------------------------------------------------
__global__ __launch_bounds__(256) void k_gemm_out(
    const unsigned short* __restrict__ aob, const unsigned short* __restrict__ wt,
    float* __restrict__ out)
{
    __shared__ char Asm[128 * 128];
    __shared__ char Bsm[128 * 128];
    int tid = threadIdx.x;
    int w = tid >> 6, lane = tid & 63, g = lane >> 4, c = lane & 15;
    int wm = w >> 1, wn = w & 1;
    int bm = blockIdx.y << 7, bn = blockIdx.x << 7;
    int rin = lane >> 3;
    int csw = ((lane & 7) ^ rin) << 4;

    f32x4 acc[4][4];
#pragma unroll
    for (int mi = 0; mi < 4; ++mi)
#pragma unroll
        for (int ni = 0; ni < 4; ++ni) acc[mi][ni] = (f32x4){0.f, 0.f, 0.f, 0.f};

    const char* Ag = (const char*)aob;
    const char* Bg = (const char*)wt;

    for (int k0 = 0; k0 < DM; k0 += 64) {
        __syncthreads();
#pragma unroll
        for (int ch = 0; ch < 4; ++ch) {
            int row = (w * 4 + ch) * 8 + rin;
            gload16(Ag + ((size_t)(bm + row) * DM + k0) * 2 + csw, Asm + (w * 4 + ch) * 1024);
            gload16(Bg + ((size_t)(bn + row) * DM + k0) * 2 + csw, Bsm + (w * 4 + ch) * 1024);
        }
        __syncthreads();
#pragma unroll
        for (int kk = 0; kk < 2; ++kk) {
            bf16x8 af[4], bfr[4];
#pragma unroll
            for (int mi = 0; mi < 4; ++mi) {
                int row = wm * 64 + mi * 16 + c;
                af[mi] = *(const bf16x8*)(Asm + ((row * 128 + kk * 64 + g * 16) ^ ((row & 7) << 4)));
            }
#pragma unroll
            for (int ni = 0; ni < 4; ++ni) {
                int row = wn * 64 + ni * 16 + c;
                bfr[ni] = *(const bf16x8*)(Bsm + ((row * 128 + kk * 64 + g * 16) ^ ((row & 7) << 4)));
            }
#pragma unroll
            for (int mi = 0; mi < 4; ++mi)
#pragma unroll
                for (int ni = 0; ni < 4; ++ni)
                    acc[mi][ni] = __builtin_amdgcn_mfma_f32_16x16x32_bf16(
                        af[mi], bfr[ni], acc[mi][ni], 0, 0, 0);
        }
    }

#pragma unroll
    for (int ni = 0; ni < 4; ++ni) {
        int n = bn + wn * 64 + ni * 16 + c;
#pragma unroll
        for (int mi = 0; mi < 4; ++mi)
#pragma unroll
            for (int r = 0; r < 4; ++r) {
                int m = bm + wm * 64 + mi * 16 + g * 4 + r;
                out[(size_t)m * DM + n] = acc[mi][ni][r];
            }
    }
}

// ---------------------------------------------------------------------------
extern "C" void kernel_launch(void* const* d_in, const int* in_sizes, int n_in,
                              void* d_out, int out_size, void* d_ws, size_t ws_size,
                              hipStream_t stream)
{
    const float* x  = (const float*)d_in[0];
    const float* wq = (const float*)d_in[1];
    const float* wo = (const float*)d_in[2];
    const float* ls = (const float*)d_in[3];
    const float* ll = (const float*)d_in[4];
    float* out = (float*)d_out;

    char* ws = (char*)d_ws;
    size_t off = 0;
    float* cosT  = (float*)(ws + off); off += (size_t)NH * NSEQ * KP * 4;        // 2 MB
    float* sinT  = (float*)(ws + off); off += (size_t)NH * NSEQ * KP * 4;        // 2 MB
    float* biasK = (float*)(ws + off); off += (size_t)NH * NSEQ * 4;             // 64 KB
    unsigned short* xb  = (unsigned short*)(ws + off); off += (size_t)MROWS * DM * 2;      // 4 MB
    unsigned short* wqT = (unsigned short*)(ws + off); off += (size_t)DM * 3 * DM * 2;     // 1.5 MB
    unsigned short* woT = (unsigned short*)(ws + off); off += (size_t)DM * DM * 2;         // 0.5 MB
    unsigned short* qbf = (unsigned short*)(ws + off); off += (size_t)MROWS * DM * 2;      // 4 MB
    unsigned short* kbf = (unsigned short*)(ws + off); off += (size_t)MROWS * DM * 2;      // 4 MB
    unsigned short* vbf = (unsigned short*)(ws + off); off += (size_t)MROWS * DM * 2;      // 4 MB
    unsigned short* aob = (unsigned short*)(ws + off); off += (size_t)MROWS * DM * 2;      // 4 MB

    k_tables<<<(NH * NSEQ + 255) / 256, 256, 0, stream>>>(ls, ll, cosT, sinT, biasK);
    k_cvt_bf16<<<(MROWS * DM / 8 + 255) / 256, 256, 0, stream>>>(x, xb, MROWS * DM / 8);
    k_transpose_bf16<<<dim3(3 * DM / 32, DM / 32), 256, 0, stream>>>(wq, wqT, DM, 3 * DM);
    k_transpose_bf16<<<dim3(DM / 32, DM / 32), 256, 0, stream>>>(wo, woT, DM, DM);
    k_gemm_qkv<<<dim3(3 * DM / 128, MROWS / 128), 256, 0, stream>>>(
        xb, wqT, cosT, sinT, qbf, kbf, vbf);
    k_attn<<<dim3(NSEQ / 64, NB * NH), 256, 0, stream>>>(
        (const __hip_bfloat16*)qbf, (const __hip_bfloat16*)kbf,
        (const __hip_bfloat16*)vbf, biasK, aob);
    k_gemm_out<<<dim3(DM / 128, MROWS / 128), 256, 0, stream>>>(aob, woT, out);
}

// Round 6
// 114.823 us; speedup vs baseline: 5.7946x; 1.0925x over previous
//
#include <hip/hip_runtime.h>
#include <hip/hip_bf16.h>
#include <math.h>

#define NSEQ 2048
#define NH 8
#define DH 64
#define KP 32
#define DM 512
#define NB 2
#define MROWS (NB * NSEQ)   // 4096

typedef short bf16x8 __attribute__((ext_vector_type(8)));
typedef float f32x4  __attribute__((ext_vector_type(4)));

static __constant__ float RZF[KP] = {
    14.134725142f, 21.022039639f, 25.01085758f,  30.424876126f, 32.935061588f,
    37.586178159f, 40.918719012f, 43.327073281f, 48.005150881f, 49.773832478f,
    52.970321478f, 56.446247697f, 59.347044003f, 60.831778525f, 65.112544048f,
    67.079810529f, 69.546401711f, 72.067157674f, 75.704690699f, 77.144840069f,
    79.33737502f,  82.910380854f, 84.735492981f, 87.425274613f, 88.809111208f,
    92.491899271f, 94.651344041f, 95.870634228f, 98.831194218f, 101.317851006f,
    103.72553804f, 105.446623052f};

static __device__ __forceinline__ unsigned short f2bf(float f) {
    unsigned int u = __float_as_uint(f);
    unsigned int r = (u + 0x7FFFu + ((u >> 16) & 1u)) >> 16;   // RNE
    return (unsigned short)r;
}

// async global->LDS, 16B per lane; LDS dest = wave-uniform base + lane*16
static __device__ __forceinline__ void gload16(const void* g, void* l) {
    __builtin_amdgcn_global_load_lds(
        (const __attribute__((address_space(1))) void*)g,
        (__attribute__((address_space(3))) void*)l, 16, 0, 0);
}

// ---------------------------------------------------------------------------
// K1: per-(h,t) tables: cos/sin[h][t][32], biasK[h][t] = (exp(ll_h)/32)*S[h][t]
// theta monotone in t => causal |sheet_i-sheet_j| telescopes to S_i - S_j;
// row-constant part cancels in softmax -> per-KEY bias only.
// ---------------------------------------------------------------------------
__global__ __launch_bounds__(256) void k_tables(
    const float* __restrict__ ls, const float* __restrict__ ll,
    float* __restrict__ cosT, float* __restrict__ sinT, float* __restrict__ biasK)
{
    int idx = blockIdx.x * 256 + threadIdx.x;       // h*NSEQ + t
    if (idx >= NH * NSEQ) return;
    int h = idx >> 11;
    int t = idx & (NSEQ - 1);
    float scale = expf(ls[h]);
    float lam32 = expf(ll[h]) * (1.0f / 32.0f);
    float tau = log1pf((float)t);
    const float TAUF = 6.2831853071795864769f;
    float ssum = 0.0f;
    float* cp = cosT + (size_t)idx * KP;
    float* sp = sinT + (size_t)idx * KP;
#pragma unroll
    for (int p = 0; p < KP; ++p) {
        float g  = RZF[p] / RZF[0];
        float th = (tau * g) * scale;
        cp[p] = cosf(th);
        sp[p] = sinf(th);
        ssum += floorf(th / TAUF);
    }
    biasK[idx] = lam32 * ssum;
}

// ---------------------------------------------------------------------------
// K1b: x (f32) -> bf16, same layout. 8 elems/thread.
// ---------------------------------------------------------------------------
__global__ __launch_bounds__(256) void k_cvt_bf16(
    const float* __restrict__ src, unsigned short* __restrict__ dst, int n8)
{
    int i = blockIdx.x * 256 + threadIdx.x;
    if (i >= n8) return;
    float4 a = ((const float4*)src)[2 * i];
    float4 b = ((const float4*)src)[2 * i + 1];
    union { unsigned short s[8]; uint4 u; } pk;
    pk.s[0] = f2bf(a.x); pk.s[1] = f2bf(a.y); pk.s[2] = f2bf(a.z); pk.s[3] = f2bf(a.w);
    pk.s[4] = f2bf(b.x); pk.s[5] = f2bf(b.y); pk.s[6] = f2bf(b.z); pk.s[7] = f2bf(b.w);
    ((uint4*)dst)[i] = pk.u;
}

// ---------------------------------------------------------------------------
// K1c: transpose-convert  src f32 [R][C] -> dst bf16 [C][R]
// ---------------------------------------------------------------------------
__global__ __launch_bounds__(256) void k_transpose_bf16(
    const float* __restrict__ src, unsigned short* __restrict__ dst, int R, int C)
{
    __shared__ float tile[32][33];
    int x0 = blockIdx.x << 5, y0 = blockIdx.y << 5;
    int tx = threadIdx.x & 31, ty = threadIdx.x >> 5;   // ty 0..7
#pragma unroll
    for (int i = 0; i < 4; ++i)
        tile[ty + i * 8][tx] = src[(size_t)(y0 + ty + i * 8) * C + x0 + tx];
    __syncthreads();
#pragma unroll
    for (int i = 0; i < 4; ++i)
        dst[(size_t)(x0 + ty + i * 8) * R + y0 + tx] = f2bf(tile[tx][ty + i * 8]);
}

// ---------------------------------------------------------------------------
// K2: MFMA GEMM  xb(4096x512 bf16) @ wqT^T, fused rotation epilogue.
// q_rot/k_rot -> [b][h][n][dh] bf16;  V -> TRANSPOSED [b][h][dh][n] bf16
// so attention can stage V^T tiles with global_load_lds (no in-loop transpose).
// ---------------------------------------------------------------------------
__global__ __launch_bounds__(256) void k_gemm_qkv(
    const unsigned short* __restrict__ xb, const unsigned short* __restrict__ wt,
    const float* __restrict__ cosT, const float* __restrict__ sinT,
    unsigned short* __restrict__ qrot, unsigned short* __restrict__ krot,
    unsigned short* __restrict__ vtout)
{
    __shared__ char Asm[128 * 128];   // 128 rows x 128B (64 bf16), swizzled
    __shared__ char Bsm[128 * 128];
    int tid = threadIdx.x;
    int w = tid >> 6, lane = tid & 63, g = lane >> 4, c = lane & 15;
    int wm = w >> 1, wn = w & 1;
    int bm = blockIdx.y << 7, bn = blockIdx.x << 7;
    int rin = lane >> 3;                       // row-in-8-row-chunk
    int csw = ((lane & 7) ^ rin) << 4;         // pre-swizzled source byte-col

    f32x4 acc[4][4];
#pragma unroll
    for (int mi = 0; mi < 4; ++mi)
#pragma unroll
        for (int ni = 0; ni < 4; ++ni) acc[mi][ni] = (f32x4){0.f, 0.f, 0.f, 0.f};

    const char* Ag = (const char*)xb;
    const char* Bg = (const char*)wt;

    for (int k0 = 0; k0 < DM; k0 += 64) {
        __syncthreads();
#pragma unroll
        for (int ch = 0; ch < 4; ++ch) {
            int row = (w * 4 + ch) * 8 + rin;
            gload16(Ag + ((size_t)(bm + row) * DM + k0) * 2 + csw, Asm + (w * 4 + ch) * 1024);
            gload16(Bg + ((size_t)(bn + row) * DM + k0) * 2 + csw, Bsm + (w * 4 + ch) * 1024);
        }
        __syncthreads();
#pragma unroll
        for (int kk = 0; kk < 2; ++kk) {
            bf16x8 af[4], bfr[4];
#pragma unroll
            for (int mi = 0; mi < 4; ++mi) {
                int row = wm * 64 + mi * 16 + c;
                af[mi] = *(const bf16x8*)(Asm + ((row * 128 + kk * 64 + g * 16) ^ ((row & 7) << 4)));
            }
#pragma unroll
            for (int ni = 0; ni < 4; ++ni) {
                int row = wn * 64 + ni * 16 + c;
                bfr[ni] = *(const bf16x8*)(Bsm + ((row * 128 + kk * 64 + g * 16) ^ ((row & 7) << 4)));
            }
#pragma unroll
            for (int mi = 0; mi < 4; ++mi)
#pragma unroll
                for (int ni = 0; ni < 4; ++ni)
                    acc[mi][ni] = __builtin_amdgcn_mfma_f32_16x16x32_bf16(
                        af[mi], bfr[ni], acc[mi][ni], 0, 0, 0);
        }
    }

    // epilogue: lane holds C[m = ..+g*4+r][n = ..+c] (wave-uniform section)
    int lane_odd = c & 1;
#pragma unroll
    for (int ni = 0; ni < 4; ++ni) {
        int n = bn + wn * 64 + ni * 16 + c;
        int sec = n >> 9;               // 0=q 1=k 2=v
        int dmod = n & 511;
        int h = dmod >> 6, dh = dmod & 63, p = dh >> 1;
        if (sec == 2) {
            // V^T: vt[(b*8+h)*64 + dh][t] ; pack 4 consecutive t per 8B store
#pragma unroll
            for (int mi = 0; mi < 4; ++mi) {
                int m0 = bm + wm * 64 + mi * 16 + g * 4;
                int b = m0 >> 11, t0 = m0 & (NSEQ - 1);
                union { unsigned short s[4]; uint2 u; } pk;
                pk.s[0] = f2bf(acc[mi][ni][0]); pk.s[1] = f2bf(acc[mi][ni][1]);
                pk.s[2] = f2bf(acc[mi][ni][2]); pk.s[3] = f2bf(acc[mi][ni][3]);
                *(uint2*)(vtout + ((size_t)(b * NH + h) * DH + dh) * NSEQ + t0) = pk.u;
            }
        } else {
            const float* cb_ = cosT + (size_t)h * NSEQ * KP + p;
            const float* sb_ = sinT + (size_t)h * NSEQ * KP + p;
            unsigned short* dst = (sec == 0) ? qrot : krot;
#pragma unroll
            for (int mi = 0; mi < 4; ++mi) {
#pragma unroll
                for (int r = 0; r < 4; ++r) {
                    int m = bm + wm * 64 + mi * 16 + g * 4 + r;
                    int b = m >> 11, t = m & (NSEQ - 1);
                    float val = acc[mi][ni][r];
                    float pv = __shfl_xor(val, 1);
                    float cv = cb_[(size_t)t * KP], sv = sb_[(size_t)t * KP];
                    float o = lane_odd ? (pv * sv + val * cv) : (val * cv - pv * sv);
                    dst[((size_t)(b * NH + h) * NSEQ + t) * DH + dh] = f2bf(o);
                }
            }
        }
    }
}

// ---------------------------------------------------------------------------
// K3: MFMA flash attention. Block = 4 waves, 64 q-rows. Heavy-first (LPT).
// Double-buffered K/V^T staged via global_load_lds with pre-swizzled source;
// stage(j+1) issued BEFORE compute(j); EXPLICIT vmcnt(0) drain before each
// barrier (do not rely on the compiler's implicit drain); defer-max (T13);
// P packed via round-4-proven f2bf.
// ---------------------------------------------------------------------------
__global__ __launch_bounds__(256) void k_attn(
    const unsigned short* __restrict__ qr, const unsigned short* __restrict__ kr,
    const unsigned short* __restrict__ vt, const float* __restrict__ biasK,
    unsigned short* __restrict__ ao)
{
    __shared__ char Kbuf[2][8192];              // [key][dh] bf16, row-swizzled
    __shared__ char Vbuf[2][8192];              // [d][key]  bf16, row-swizzled
    __shared__ __hip_bfloat16 Pl[4][16 * 64];   // per-wave [q][key], row-swizzled
    __shared__ float Bk[2][64];

    int bh = blockIdx.y;            // b*8 + h
    int b = bh >> 3, h = bh & 7;
    int qt = (gridDim.x - 1) - blockIdx.x;      // heavy-first (LPT)
    int q0 = qt << 6;
    int tid = threadIdx.x;
    int w    = tid >> 6;
    int lane = tid & 63;
    int g    = lane >> 4;
    int c    = lane & 15;
    char* Pb = (char*)(&Pl[w][0]);

    const char* kb  = (const char*)(kr + (size_t)bh * NSEQ * DH);
    const char* vtb = (const char*)(vt + (size_t)bh * DH * NSEQ);
    const unsigned short* qb = qr + (size_t)bh * NSEQ * DH;
    const float* bkrow = biasK + (size_t)h * NSEQ;

    int qg = q0 + (w << 4) + c;

    // Q fragments (B-operand of swapped QK^T)
    bf16x8 qf[2];
#pragma unroll
    for (int s = 0; s < 2; ++s)
        qf[s] = *(const bf16x8*)(qb + (size_t)qg * DH + s * 32 + g * 8);

    f32x4 oa[4];
#pragma unroll
    for (int dt = 0; dt < 4; ++dt) oa[dt] = (f32x4){0.f, 0.f, 0.f, 0.f};
    float mr = -3.0e38f, lr = 0.0f;

    int rin = lane >> 3;
    int swz = ((lane & 7) ^ rin) << 4;          // pre-swizzled source byte-col

    // stage one 64-key tile into buffer `cur`: wave w does K/V chunks 2w,2w+1
    auto stage = [&](int buf, int j0) {
#pragma unroll
        for (int i = 0; i < 2; ++i) {
            int ch = w * 2 + i;
            int row = ch * 8 + rin;
            gload16(kb  + (size_t)(j0 + row) * 128 + swz, Kbuf[buf] + ch * 1024);
            gload16(vtb + (size_t)row * (NSEQ * 2) + (size_t)j0 * 2 + swz,
                    Vbuf[buf] + ch * 1024);
        }
        if (tid < 64) Bk[buf][tid] = bkrow[j0 + tid];
    };

    int ntiles = qt + 1;
    stage(0, 0);
    asm volatile("s_waitcnt vmcnt(0)" ::: "memory");   // explicit DMA drain
    __syncthreads();
    int cur = 0;

    for (int tile = 0; tile < ntiles; ++tile) {
        int j0 = tile << 6;
        if (tile + 1 < ntiles) stage(cur ^ 1, j0 + 64);   // issue-early (T14)

        // ---- S^T = K · Q^T ----
        f32x4 st[4];
#pragma unroll
        for (int kt = 0; kt < 4; ++kt) st[kt] = (f32x4){0.f, 0.f, 0.f, 0.f};
#pragma unroll
        for (int s = 0; s < 2; ++s) {
#pragma unroll
            for (int kt = 0; kt < 4; ++kt) {
                int row = kt * 16 + c;
                bf16x8 af = *(const bf16x8*)(Kbuf[cur] +
                    ((row * 128 + s * 64 + g * 16) ^ ((row & 7) << 4)));
                st[kt] = __builtin_amdgcn_mfma_f32_16x16x32_bf16(af, qf[s], st[kt], 0, 0, 0);
            }
        }

        // ---- bias + causal mask; lane owns S^T[key=kt*16+g*4+r4][q=c] ----
        bool lastT = (tile == ntiles - 1);
        float sv[16];
#pragma unroll
        for (int kt = 0; kt < 4; ++kt) {
#pragma unroll
            for (int r4 = 0; r4 < 4; ++r4) {
                int ki = kt * 16 + g * 4 + r4;
                float vl = st[kt][r4] * 0.125f + Bk[cur][ki];
                if (lastT && (j0 + ki > qg)) vl = -3.0e38f;
                sv[kt * 4 + r4] = vl;
            }
        }

        // ---- online softmax with defer-max (T13) ----
        float m16 = sv[0];
#pragma unroll
        for (int i = 1; i < 16; ++i) m16 = fmaxf(m16, sv[i]);
        m16 = fmaxf(m16, __shfl_xor(m16, 16));
        m16 = fmaxf(m16, __shfl_xor(m16, 32));
        if (__any(m16 > mr + 8.0f)) {
            float mt = fmaxf(mr, m16);
            float corr = __expf(mr - mt);
            mr = mt;
            lr *= corr;
            float corrO[4];
#pragma unroll
            for (int r4 = 0; r4 < 4; ++r4) corrO[r4] = __shfl(corr, g * 4 + r4);
#pragma unroll
            for (int dt = 0; dt < 4; ++dt)
#pragma unroll
                for (int r4 = 0; r4 < 4; ++r4) oa[dt][r4] *= corrO[r4];
        }
        float psum = 0.0f;
        unsigned int pw[8];
#pragma unroll
        for (int i = 0; i < 8; ++i) {
            float p0 = __expf(sv[2 * i]     - mr);
            float p1 = __expf(sv[2 * i + 1] - mr);
            psum += p0 + p1;
            pw[i] = (unsigned int)f2bf(p0) | ((unsigned int)f2bf(p1) << 16);
        }
        lr += psum;

        // ---- P (bf16) -> per-wave LDS: [q=c][key] ----
#pragma unroll
        for (int kt = 0; kt < 4; ++kt) {
            uint2 u2; u2.x = pw[2 * kt]; u2.y = pw[2 * kt + 1];
            *(uint2*)(Pb + ((c * 128 + kt * 32 + g * 8) ^ ((c & 7) << 4))) = u2;
        }

        // ---- O += P · V ----
#pragma unroll
        for (int s = 0; s < 2; ++s) {
            bf16x8 pa = *(const bf16x8*)(Pb + ((c * 128 + s * 64 + g * 16) ^ ((c & 7) << 4)));
#pragma unroll
            for (int dt = 0; dt < 4; ++dt) {
                int d = dt * 16 + c;
                bf16x8 vf = *(const bf16x8*)(Vbuf[cur] +
                    ((d * 128 + s * 64 + g * 16) ^ ((d & 7) << 4)));
                oa[dt] = __builtin_amdgcn_mfma_f32_16x16x32_bf16(pa, vf, oa[dt], 0, 0, 0);
            }
        }
        asm volatile("s_waitcnt vmcnt(0)" ::: "memory");   // drain next-tile DMA
        __syncthreads();
        cur ^= 1;
    }

    // ---- final: l reduce, scale, store (lane holds O[q=g*4+r4][d=dt*16+c]) ----
    lr += __shfl_xor(lr, 16);
    lr += __shfl_xor(lr, 32);
    float inv = 1.0f / lr;
    float invO[4];
#pragma unroll
    for (int r4 = 0; r4 < 4; ++r4) invO[r4] = __shfl(inv, g * 4 + r4);
#pragma unroll
    for (int dt = 0; dt < 4; ++dt) {
#pragma unroll
        for (int r4 = 0; r4 < 4; ++r4) {
            int row = q0 + (w << 4) + g * 4 + r4;
            ao[((size_t)b * NSEQ + row) * DM + h * DH + dt * 16 + c] =
                f2bf(oa[dt][r4] * invO[r4]);
        }
    }
}

// ---------------------------------------------------------------------------
// K4: MFMA GEMM  aob(4096x512 bf16) @ woT^T -> f32 out
// ---------------------------------------------------------------------------
__global__ __launch_bounds__(256) void k_gemm_out(
    const unsigned short* __restrict__ aob, const unsigned short* __restrict__ wt,
    float* __restrict__ out)
{
    __shared__ char Asm[128 * 128];
    __shared__ char Bsm[128 * 128];
    int tid = threadIdx.x;
    int w = tid >> 6, lane = tid & 63, g = lane >> 4, c = lane & 15;
    int wm = w >> 1, wn = w & 1;
    int bm = blockIdx.y << 7, bn = blockIdx.x << 7;
    int rin = lane >> 3;
    int csw = ((lane & 7) ^ rin) << 4;

    f32x4 acc[4][4];
#pragma unroll
    for (int mi = 0; mi < 4; ++mi)
#pragma unroll
        for (int ni = 0; ni < 4; ++ni) acc[mi][ni] = (f32x4){0.f, 0.f, 0.f, 0.f};

    const char* Ag = (const char*)aob;
    const char* Bg = (const char*)wt;

    for (int k0 = 0; k0 < DM; k0 += 64) {
        __syncthreads();
#pragma unroll
        for (int ch = 0; ch < 4; ++ch) {
            int row = (w * 4 + ch) * 8 + rin;
            gload16(Ag + ((size_t)(bm + row) * DM + k0) * 2 + csw, Asm + (w * 4 + ch) * 1024);
            gload16(Bg + ((size_t)(bn + row) * DM + k0) * 2 + csw, Bsm + (w * 4 + ch) * 1024);
        }
        __syncthreads();
#pragma unroll
        for (int kk = 0; kk < 2; ++kk) {
            bf16x8 af[4], bfr[4];
#pragma unroll
            for (int mi = 0; mi < 4; ++mi) {
                int row = wm * 64 + mi * 16 + c;
                af[mi] = *(const bf16x8*)(Asm + ((row * 128 + kk * 64 + g * 16) ^ ((row & 7) << 4)));
            }
#pragma unroll
            for (int ni = 0; ni < 4; ++ni) {
                int row = wn * 64 + ni * 16 + c;
                bfr[ni] = *(const bf16x8*)(Bsm + ((row * 128 + kk * 64 + g * 16) ^ ((row & 7) << 4)));
            }
#pragma unroll
            for (int mi = 0; mi < 4; ++mi)
#pragma unroll
                for (int ni = 0; ni < 4; ++ni)
                    acc[mi][ni] = __builtin_amdgcn_mfma_f32_16x16x32_bf16(
                        af[mi], bfr[ni], acc[mi][ni], 0, 0, 0);
        }
    }

#pragma unroll
    for (int ni = 0; ni < 4; ++ni) {
        int n = bn + wn * 64 + ni * 16 + c;
#pragma unroll
        for (int mi = 0; mi < 4; ++mi)
#pragma unroll
            for (int r = 0; r < 4; ++r) {
                int m = bm + wm * 64 + mi * 16 + g * 4 + r;
                out[(size_t)m * DM + n] = acc[mi][ni][r];
            }
    }
}

// ---------------------------------------------------------------------------
extern "C" void kernel_launch(void* const* d_in, const int* in_sizes, int n_in,
                              void* d_out, int out_size, void* d_ws, size_t ws_size,
                              hipStream_t stream)
{
    const float* x  = (const float*)d_in[0];
    const float* wq = (const float*)d_in[1];
    const float* wo = (const float*)d_in[2];
    const float* ls = (const float*)d_in[3];
    const float* ll = (const float*)d_in[4];
    float* out = (float*)d_out;

    char* ws = (char*)d_ws;
    size_t off = 0;
    float* cosT  = (float*)(ws + off); off += (size_t)NH * NSEQ * KP * 4;        // 2 MB
    float* sinT  = (float*)(ws + off); off += (size_t)NH * NSEQ * KP * 4;        // 2 MB
    float* biasK = (float*)(ws + off); off += (size_t)NH * NSEQ * 4;             // 64 KB
    unsigned short* xb  = (unsigned short*)(ws + off); off += (size_t)MROWS * DM * 2;      // 4 MB
    unsigned short* wqT = (unsigned short*)(ws + off); off += (size_t)DM * 3 * DM * 2;     // 1.5 MB
    unsigned short* woT = (unsigned short*)(ws + off); off += (size_t)DM * DM * 2;         // 0.5 MB
    unsigned short* qbf = (unsigned short*)(ws + off); off += (size_t)MROWS * DM * 2;      // 4 MB
    unsigned short* kbf = (unsigned short*)(ws + off); off += (size_t)MROWS * DM * 2;      // 4 MB
    unsigned short* vtb = (unsigned short*)(ws + off); off += (size_t)MROWS * DM * 2;      // 4 MB
    unsigned short* aob = (unsigned short*)(ws + off); off += (size_t)MROWS * DM * 2;      // 4 MB

    k_tables<<<(NH * NSEQ + 255) / 256, 256, 0, stream>>>(ls, ll, cosT, sinT, biasK);
    k_cvt_bf16<<<(MROWS * DM / 8 + 255) / 256, 256, 0, stream>>>(x, xb, MROWS * DM / 8);
    k_transpose_bf16<<<dim3(3 * DM / 32, DM / 32), 256, 0, stream>>>(wq, wqT, DM, 3 * DM);
    k_transpose_bf16<<<dim3(DM / 32, DM / 32), 256, 0, stream>>>(wo, woT, DM, DM);
    k_gemm_qkv<<<dim3(3 * DM / 128, MROWS / 128), 256, 0, stream>>>(
        xb, wqT, cosT, sinT, qbf, kbf, vtb);
    k_attn<<<dim3(NSEQ / 64, NB * NH), 256, 0, stream>>>(qbf, kbf, vtb, biasK, aob);
    k_gemm_out<<<dim3(DM / 128, MROWS / 128), 256, 0, stream>>>(aob, woT, out);
}

// Round 7
// 101.490 us; speedup vs baseline: 6.5559x; 1.1314x over previous
//
#include <hip/hip_runtime.h>
#include <hip/hip_bf16.h>
#include <math.h>

#define NSEQ 2048
#define NH 8
#define DH 64
#define KP 32
#define DM 512
#define NB 2
#define MROWS (NB * NSEQ)   // 4096
#define SLOTS 80            // key-chunk slots per (b,h): sum_{g=0..3} 8*(g+1)

typedef short bf16x8 __attribute__((ext_vector_type(8)));
typedef float f32x4  __attribute__((ext_vector_type(4)));

static __constant__ float RZF[KP] = {
    14.134725142f, 21.022039639f, 25.01085758f,  30.424876126f, 32.935061588f,
    37.586178159f, 40.918719012f, 43.327073281f, 48.005150881f, 49.773832478f,
    52.970321478f, 56.446247697f, 59.347044003f, 60.831778525f, 65.112544048f,
    67.079810529f, 69.546401711f, 72.067157674f, 75.704690699f, 77.144840069f,
    79.33737502f,  82.910380854f, 84.735492981f, 87.425274613f, 88.809111208f,
    92.491899271f, 94.651344041f, 95.870634228f, 98.831194218f, 101.317851006f,
    103.72553804f, 105.446623052f};

static __device__ __forceinline__ unsigned short f2bf(float f) {
    unsigned int u = __float_as_uint(f);
    unsigned int r = (u + 0x7FFFu + ((u >> 16) & 1u)) >> 16;   // RNE
    return (unsigned short)r;
}
static __device__ __forceinline__ float bf2f(unsigned short s) {
    return __uint_as_float((unsigned int)s << 16);
}

// async global->LDS, 16B per lane; LDS dest = wave-uniform base + lane*16
static __device__ __forceinline__ void gload16(const void* g, void* l) {
    __builtin_amdgcn_global_load_lds(
        (const __attribute__((address_space(1))) void*)g,
        (__attribute__((address_space(3))) void*)l, 16, 0, 0);
}

// ---------------------------------------------------------------------------
// K1: per-(h,t) tables: cos/sin[h][t][32], biasK[h][t] = (exp(ll_h)/32)*S[h][t]
// theta monotone in t => causal |sheet_i-sheet_j| telescopes to S_i - S_j;
// row-constant part cancels in softmax -> per-KEY bias only.
// ---------------------------------------------------------------------------
__global__ __launch_bounds__(256) void k_tables(
    const float* __restrict__ ls, const float* __restrict__ ll,
    float* __restrict__ cosT, float* __restrict__ sinT, float* __restrict__ biasK)
{
    int idx = blockIdx.x * 256 + threadIdx.x;       // h*NSEQ + t
    if (idx >= NH * NSEQ) return;
    int h = idx >> 11;
    int t = idx & (NSEQ - 1);
    float scale = expf(ls[h]);
    float lam32 = expf(ll[h]) * (1.0f / 32.0f);
    float tau = log1pf((float)t);
    const float TAUF = 6.2831853071795864769f;
    float ssum = 0.0f;
    float* cp = cosT + (size_t)idx * KP;
    float* sp = sinT + (size_t)idx * KP;
#pragma unroll
    for (int p = 0; p < KP; ++p) {
        float g  = RZF[p] / RZF[0];
        float th = (tau * g) * scale;
        cp[p] = cosf(th);
        sp[p] = sinf(th);
        ssum += floorf(th / TAUF);
    }
    biasK[idx] = lam32 * ssum;
}

// ---------------------------------------------------------------------------
// K1b: x (f32) -> bf16, same layout. 8 elems/thread.
// ---------------------------------------------------------------------------
__global__ __launch_bounds__(256) void k_cvt_bf16(
    const float* __restrict__ src, unsigned short* __restrict__ dst, int n8)
{
    int i = blockIdx.x * 256 + threadIdx.x;
    if (i >= n8) return;
    float4 a = ((const float4*)src)[2 * i];
    float4 b = ((const float4*)src)[2 * i + 1];
    union { unsigned short s[8]; uint4 u; } pk;
    pk.s[0] = f2bf(a.x); pk.s[1] = f2bf(a.y); pk.s[2] = f2bf(a.z); pk.s[3] = f2bf(a.w);
    pk.s[4] = f2bf(b.x); pk.s[5] = f2bf(b.y); pk.s[6] = f2bf(b.z); pk.s[7] = f2bf(b.w);
    ((uint4*)dst)[i] = pk.u;
}

// ---------------------------------------------------------------------------
// K1c: transpose-convert  src f32 [R][C] -> dst bf16 [C][R]
// ---------------------------------------------------------------------------
__global__ __launch_bounds__(256) void k_transpose_bf16(
    const float* __restrict__ src, unsigned short* __restrict__ dst, int R, int C)
{
    __shared__ float tile[32][33];
    int x0 = blockIdx.x << 5, y0 = blockIdx.y << 5;
    int tx = threadIdx.x & 31, ty = threadIdx.x >> 5;   // ty 0..7
#pragma unroll
    for (int i = 0; i < 4; ++i)
        tile[ty + i * 8][tx] = src[(size_t)(y0 + ty + i * 8) * C + x0 + tx];
    __syncthreads();
#pragma unroll
    for (int i = 0; i < 4; ++i)
        dst[(size_t)(x0 + ty + i * 8) * R + y0 + tx] = f2bf(tile[tx][ty + i * 8]);
}

// ---------------------------------------------------------------------------
// K2: MFMA GEMM  xb(4096x512 bf16) @ wqT^T, fused rotation epilogue.
// q_rot/k_rot -> [b][h][n][dh] bf16;  V -> TRANSPOSED [b][h][dh][n] bf16.
// ---------------------------------------------------------------------------
__global__ __launch_bounds__(256) void k_gemm_qkv(
    const unsigned short* __restrict__ xb, const unsigned short* __restrict__ wt,
    const float* __restrict__ cosT, const float* __restrict__ sinT,
    unsigned short* __restrict__ qrot, unsigned short* __restrict__ krot,
    unsigned short* __restrict__ vtout)
{
    __shared__ char Asm[128 * 128];   // 128 rows x 128B (64 bf16), swizzled
    __shared__ char Bsm[128 * 128];
    int tid = threadIdx.x;
    int w = tid >> 6, lane = tid & 63, g = lane >> 4, c = lane & 15;
    int wm = w >> 1, wn = w & 1;
    int bm = blockIdx.y << 7, bn = blockIdx.x << 7;
    int rin = lane >> 3;                       // row-in-8-row-chunk
    int csw = ((lane & 7) ^ rin) << 4;         // pre-swizzled source byte-col

    f32x4 acc[4][4];
#pragma unroll
    for (int mi = 0; mi < 4; ++mi)
#pragma unroll
        for (int ni = 0; ni < 4; ++ni) acc[mi][ni] = (f32x4){0.f, 0.f, 0.f, 0.f};

    const char* Ag = (const char*)xb;
    const char* Bg = (const char*)wt;

    for (int k0 = 0; k0 < DM; k0 += 64) {
        __syncthreads();
#pragma unroll
        for (int ch = 0; ch < 4; ++ch) {
            int row = (w * 4 + ch) * 8 + rin;
            gload16(Ag + ((size_t)(bm + row) * DM + k0) * 2 + csw, Asm + (w * 4 + ch) * 1024);
            gload16(Bg + ((size_t)(bn + row) * DM + k0) * 2 + csw, Bsm + (w * 4 + ch) * 1024);
        }
        asm volatile("s_waitcnt vmcnt(0)" ::: "memory");
        __syncthreads();
#pragma unroll
        for (int kk = 0; kk < 2; ++kk) {
            bf16x8 af[4], bfr[4];
#pragma unroll
            for (int mi = 0; mi < 4; ++mi) {
                int row = wm * 64 + mi * 16 + c;
                af[mi] = *(const bf16x8*)(Asm + ((row * 128 + kk * 64 + g * 16) ^ ((row & 7) << 4)));
            }
#pragma unroll
            for (int ni = 0; ni < 4; ++ni) {
                int row = wn * 64 + ni * 16 + c;
                bfr[ni] = *(const bf16x8*)(Bsm + ((row * 128 + kk * 64 + g * 16) ^ ((row & 7) << 4)));
            }
#pragma unroll
            for (int mi = 0; mi < 4; ++mi)
#pragma unroll
                for (int ni = 0; ni < 4; ++ni)
                    acc[mi][ni] = __builtin_amdgcn_mfma_f32_16x16x32_bf16(
                        af[mi], bfr[ni], acc[mi][ni], 0, 0, 0);
        }
    }

    // epilogue: lane holds C[m = ..+g*4+r][n = ..+c] (wave-uniform section)
    int lane_odd = c & 1;
#pragma unroll
    for (int ni = 0; ni < 4; ++ni) {
        int n = bn + wn * 64 + ni * 16 + c;
        int sec = n >> 9;               // 0=q 1=k 2=v
        int dmod = n & 511;
        int h = dmod >> 6, dh = dmod & 63, p = dh >> 1;
        if (sec == 2) {
            // V^T: vt[(b*8+h)*64 + dh][t] ; pack 4 consecutive t per 8B store
#pragma unroll
            for (int mi = 0; mi < 4; ++mi) {
                int m0 = bm + wm * 64 + mi * 16 + g * 4;
                int b = m0 >> 11, t0 = m0 & (NSEQ - 1);
                union { unsigned short s[4]; uint2 u; } pk;
                pk.s[0] = f2bf(acc[mi][ni][0]); pk.s[1] = f2bf(acc[mi][ni][1]);
                pk.s[2] = f2bf(acc[mi][ni][2]); pk.s[3] = f2bf(acc[mi][ni][3]);
                *(uint2*)(vtout + ((size_t)(b * NH + h) * DH + dh) * NSEQ + t0) = pk.u;
            }
        } else {
            const float* cb_ = cosT + (size_t)h * NSEQ * KP + p;
            const float* sb_ = sinT + (size_t)h * NSEQ * KP + p;
            unsigned short* dst = (sec == 0) ? qrot : krot;
#pragma unroll
            for (int mi = 0; mi < 4; ++mi) {
#pragma unroll
                for (int r = 0; r < 4; ++r) {
                    int m = bm + wm * 64 + mi * 16 + g * 4 + r;
                    int b = m >> 11, t = m & (NSEQ - 1);
                    float val = acc[mi][ni][r];
                    float pv = __shfl_xor(val, 1);
                    float cv = cb_[(size_t)t * KP], sv = sb_[(size_t)t * KP];
                    float o = lane_odd ? (pv * sv + val * cv) : (val * cv - pv * sv);
                    dst[((size_t)(b * NH + h) * NSEQ + t) * DH + dh] = f2bf(o);
                }
            }
        }
    }
}

// ---------------------------------------------------------------------------
// K3: split-K MFMA flash attention, phase 1.
// Grid: (SLOTS=80, 16 bh). Slot s decodes to (qt, ci): per 8-qt octave g,
// qt has g+1 chunks of <=8 key-tiles (512 keys). Near-uniform block work ->
// 1280 blocks (5/CU), single-buffered staging, TLP hides latency.
// Single-chunk qt (<=7) writes final bf16 output; else unnormalized partial
// O (bf16) + per-row (m, l) for phase-2 merge.
// ---------------------------------------------------------------------------
__global__ __launch_bounds__(256) void k_attn(
    const unsigned short* __restrict__ qr, const unsigned short* __restrict__ kr,
    const unsigned short* __restrict__ vt, const float* __restrict__ biasK,
    unsigned short* __restrict__ ao, unsigned short* __restrict__ opart,
    float* __restrict__ mlpart)
{
    __shared__ char Kbuf[8192];                 // [key][dh] bf16, row-swizzled
    __shared__ char Vbuf[8192];                 // [d][key]  bf16, row-swizzled
    __shared__ __hip_bfloat16 Pl[4][16 * 64];   // per-wave [q][key], row-swizzled
    __shared__ float Bk[64];

    int bh = blockIdx.y;            // b*8 + h
    int b = bh >> 3, h = bh & 7;
    // decode slot -> (qt, ci)
    int s = blockIdx.x;
    int g4 = 0, base = 0;
    while (s >= base + 8 * (g4 + 1)) { base += 8 * (g4 + 1); ++g4; }
    int rem = s - base;
    int qt = g4 * 8 + rem / (g4 + 1);
    int ci = rem % (g4 + 1);
    int nch = (qt >> 3) + 1;
    int t0 = ci * 8;
    int t1 = min(t0 + 8, qt + 1);

    int q0 = qt << 6;
    int tid = threadIdx.x;
    int w    = tid >> 6;
    int lane = tid & 63;
    int g    = lane >> 4;
    int c    = lane & 15;
    char* Pb = (char*)(&Pl[w][0]);

    const char* kb  = (const char*)(kr + (size_t)bh * NSEQ * DH);
    const char* vtb = (const char*)(vt + (size_t)bh * DH * NSEQ);
    const unsigned short* qb = qr + (size_t)bh * NSEQ * DH;
    const float* bkrow = biasK + (size_t)h * NSEQ;

    int qg = q0 + (w << 4) + c;     // this lane's softmax row (q = c)

    // Q fragments (B-operand of swapped QK^T)
    bf16x8 qf[2];
#pragma unroll
    for (int sl = 0; sl < 2; ++sl)
        qf[sl] = *(const bf16x8*)(qb + (size_t)qg * DH + sl * 32 + g * 8);

    f32x4 oa[4];
#pragma unroll
    for (int dt = 0; dt < 4; ++dt) oa[dt] = (f32x4){0.f, 0.f, 0.f, 0.f};
    float mr = -3.0e38f, lr = 0.0f;

    int rin = lane >> 3;
    int swz = ((lane & 7) ^ rin) << 4;          // pre-swizzled source byte-col

    for (int tile = t0; tile < t1; ++tile) {
        int j0 = tile << 6;
        // ---- stage K / V^T / bias (single buffer) ----
#pragma unroll
        for (int i = 0; i < 2; ++i) {
            int ch = w * 2 + i;
            int row = ch * 8 + rin;
            gload16(kb  + (size_t)(j0 + row) * 128 + swz, Kbuf + ch * 1024);
            gload16(vtb + (size_t)row * (NSEQ * 2) + (size_t)j0 * 2 + swz,
                    Vbuf + ch * 1024);
        }
        if (tid < 64) Bk[tid] = bkrow[j0 + tid];
        asm volatile("s_waitcnt vmcnt(0)" ::: "memory");   // explicit DMA drain
        __syncthreads();

        // ---- S^T = K · Q^T ----
        f32x4 st[4];
#pragma unroll
        for (int kt = 0; kt < 4; ++kt) st[kt] = (f32x4){0.f, 0.f, 0.f, 0.f};
#pragma unroll
        for (int sl = 0; sl < 2; ++sl) {
#pragma unroll
            for (int kt = 0; kt < 4; ++kt) {
                int row = kt * 16 + c;
                bf16x8 af = *(const bf16x8*)(Kbuf +
                    ((row * 128 + sl * 64 + g * 16) ^ ((row & 7) << 4)));
                st[kt] = __builtin_amdgcn_mfma_f32_16x16x32_bf16(af, qf[sl], st[kt], 0, 0, 0);
            }
        }

        // ---- bias + causal mask; lane owns S^T[key=kt*16+g*4+r4][q=c] ----
        bool diagT = (tile == qt);
        float sv[16];
#pragma unroll
        for (int kt = 0; kt < 4; ++kt) {
#pragma unroll
            for (int r4 = 0; r4 < 4; ++r4) {
                int ki = kt * 16 + g * 4 + r4;
                float vl = st[kt][r4] * 0.125f + Bk[ki];
                if (diagT && (j0 + ki > qg)) vl = -3.0e38f;
                sv[kt * 4 + r4] = vl;
            }
        }

        // ---- online softmax with defer-max (T13) ----
        float m16 = sv[0];
#pragma unroll
        for (int i = 1; i < 16; ++i) m16 = fmaxf(m16, sv[i]);
        m16 = fmaxf(m16, __shfl_xor(m16, 16));
        m16 = fmaxf(m16, __shfl_xor(m16, 32));
        if (__any(m16 > mr + 8.0f)) {
            float mt = fmaxf(mr, m16);
            float corr = __expf(mr - mt);
            mr = mt;
            lr *= corr;
            float corrO[4];
#pragma unroll
            for (int r4 = 0; r4 < 4; ++r4) corrO[r4] = __shfl(corr, g * 4 + r4);
#pragma unroll
            for (int dt = 0; dt < 4; ++dt)
#pragma unroll
                for (int r4 = 0; r4 < 4; ++r4) oa[dt][r4] *= corrO[r4];
        }
        float psum = 0.0f;
        unsigned int pw[8];
#pragma unroll
        for (int i = 0; i < 8; ++i) {
            float p0 = __expf(sv[2 * i]     - mr);
            float p1 = __expf(sv[2 * i + 1] - mr);
            psum += p0 + p1;
            pw[i] = (unsigned int)f2bf(p0) | ((unsigned int)f2bf(p1) << 16);
        }
        lr += psum;

        // ---- P (bf16) -> per-wave LDS: [q=c][key] ----
#pragma unroll
        for (int kt = 0; kt < 4; ++kt) {
            uint2 u2; u2.x = pw[2 * kt]; u2.y = pw[2 * kt + 1];
            *(uint2*)(Pb + ((c * 128 + kt * 32 + g * 8) ^ ((c & 7) << 4))) = u2;
        }

        // ---- O += P · V ----
#pragma unroll
        for (int sl = 0; sl < 2; ++sl) {
            bf16x8 pa = *(const bf16x8*)(Pb + ((c * 128 + sl * 64 + g * 16) ^ ((c & 7) << 4)));
#pragma unroll
            for (int dt = 0; dt < 4; ++dt) {
                int d = dt * 16 + c;
                bf16x8 vf = *(const bf16x8*)(Vbuf +
                    ((d * 128 + sl * 64 + g * 16) ^ ((d & 7) << 4)));
                oa[dt] = __builtin_amdgcn_mfma_f32_16x16x32_bf16(pa, vf, oa[dt], 0, 0, 0);
            }
        }
        __syncthreads();   // all waves done reading before next stage overwrites
    }

    // ---- epilogue: reduce l across groups; lane holds O[q=g*4+r4][d=dt*16+c]
    lr += __shfl_xor(lr, 16);
    lr += __shfl_xor(lr, 32);
    if (nch == 1) {
        float inv = 1.0f / lr;
        float invO[4];
#pragma unroll
        for (int r4 = 0; r4 < 4; ++r4) invO[r4] = __shfl(inv, g * 4 + r4);
#pragma unroll
        for (int dt = 0; dt < 4; ++dt)
#pragma unroll
            for (int r4 = 0; r4 < 4; ++r4) {
                int row = q0 + (w << 4) + g * 4 + r4;
                ao[((size_t)b * NSEQ + row) * DM + h * DH + dt * 16 + c] =
                    f2bf(oa[dt][r4] * invO[r4]);
            }
    } else {
        size_t obase = ((size_t)bh * SLOTS + blockIdx.x) * (64 * 64);
#pragma unroll
        for (int dt = 0; dt < 4; ++dt)
#pragma unroll
            for (int r4 = 0; r4 < 4; ++r4) {
                int row = (w << 4) + g * 4 + r4;     // row within block
                opart[obase + row * 64 + dt * 16 + c] = f2bf(oa[dt][r4]);
            }
        if (g == 0) {   // one lane-group per row writes (m, l); row = w*16 + c
            size_t mb = (((size_t)bh * SLOTS + blockIdx.x) * 64 + (w << 4) + c) * 2;
            mlpart[mb]     = mr;
            mlpart[mb + 1] = lr;
        }
    }
}

// ---------------------------------------------------------------------------
// K3b: phase-2 merge for qt >= 8 (2..4 chunks). Grid (24, 16bh), 256 thr.
// Thread: row = tid/4 (0..63), d0 = (tid%4)*16; merges chunk partials:
// M = max m_c; out = (sum O_c e^{m_c-M}) / (sum l_c e^{m_c-M}).
// ---------------------------------------------------------------------------
__global__ __launch_bounds__(256) void k_merge(
    const unsigned short* __restrict__ opart, const float* __restrict__ mlpart,
    unsigned short* __restrict__ ao)
{
    int bh = blockIdx.y;
    int b = bh >> 3, h = bh & 7;
    int qt = 8 + blockIdx.x;              // 8..31
    int g4 = qt >> 3;                     // 1..3
    int nch = g4 + 1;
    int slot0 = 4 * g4 * (g4 + 1) + (qt - 8 * g4) * (g4 + 1);
    int tid = threadIdx.x;
    int row = tid >> 2;
    int d0 = (tid & 3) << 4;

    size_t pbase = ((size_t)bh * SLOTS + slot0) * 4096 + row * 64 + d0;
    size_t mbase = (((size_t)bh * SLOTS + slot0) * 64 + row) * 2;

    float M = -3.0e38f;
#pragma unroll
    for (int cc = 0; cc < 4; ++cc)
        if (cc < nch) M = fmaxf(M, mlpart[mbase + (size_t)cc * 128]);

    float L = 0.0f;
    float o[16];
#pragma unroll
    for (int i = 0; i < 16; ++i) o[i] = 0.0f;
#pragma unroll
    for (int cc = 0; cc < 4; ++cc) {
        if (cc < nch) {
            float mc = mlpart[mbase + (size_t)cc * 128];
            float lc = mlpart[mbase + (size_t)cc * 128 + 1];
            float wgt = __expf(mc - M);
            L += lc * wgt;
            union { uint4 u; unsigned short sh[8]; } lo, hi;
            lo.u = *(const uint4*)(opart + pbase + (size_t)cc * 4096);
            hi.u = *(const uint4*)(opart + pbase + (size_t)cc * 4096 + 8);
#pragma unroll
            for (int i = 0; i < 8; ++i) {
                o[i]     += bf2f(lo.sh[i]) * wgt;
                o[i + 8] += bf2f(hi.sh[i]) * wgt;
            }
        }
    }
    float invL = 1.0f / L;
    int grow = (qt << 6) + row;
    unsigned short* dst = ao + ((size_t)b * NSEQ + grow) * DM + h * DH + d0;
    union { unsigned short sh[8]; uint4 u; } p0, p1;
#pragma unroll
    for (int i = 0; i < 8; ++i) {
        p0.sh[i] = f2bf(o[i] * invL);
        p1.sh[i] = f2bf(o[i + 8] * invL);
    }
    *(uint4*)dst = p0.u;
    *(uint4*)(dst + 8) = p1.u;
}

// ---------------------------------------------------------------------------
// K4: MFMA GEMM  aob(4096x512 bf16) @ woT^T -> f32 out
// ---------------------------------------------------------------------------
__global__ __launch_bounds__(256) void k_gemm_out(
    const unsigned short* __restrict__ aob, const unsigned short* __restrict__ wt,
    float* __restrict__ out)
{
    __shared__ char Asm[128 * 128];
    __shared__ char Bsm[128 * 128];
    int tid = threadIdx.x;
    int w = tid >> 6, lane = tid & 63, g = lane >> 4, c = lane & 15;
    int wm = w >> 1, wn = w & 1;
    int bm = blockIdx.y << 7, bn = blockIdx.x << 7;
    int rin = lane >> 3;
    int csw = ((lane & 7) ^ rin) << 4;

    f32x4 acc[4][4];
#pragma unroll
    for (int mi = 0; mi < 4; ++mi)
#pragma unroll
        for (int ni = 0; ni < 4; ++ni) acc[mi][ni] = (f32x4){0.f, 0.f, 0.f, 0.f};

    const char* Ag = (const char*)aob;
    const char* Bg = (const char*)wt;

    for (int k0 = 0; k0 < DM; k0 += 64) {
        __syncthreads();
#pragma unroll
        for (int ch = 0; ch < 4; ++ch) {
            int row = (w * 4 + ch) * 8 + rin;
            gload16(Ag + ((size_t)(bm + row) * DM + k0) * 2 + csw, Asm + (w * 4 + ch) * 1024);
            gload16(Bg + ((size_t)(bn + row) * DM + k0) * 2 + csw, Bsm + (w * 4 + ch) * 1024);
        }
        asm volatile("s_waitcnt vmcnt(0)" ::: "memory");
        __syncthreads();
#pragma unroll
        for (int kk = 0; kk < 2; ++kk) {
            bf16x8 af[4], bfr[4];
#pragma unroll
            for (int mi = 0; mi < 4; ++mi) {
                int row = wm * 64 + mi * 16 + c;
                af[mi] = *(const bf16x8*)(Asm + ((row * 128 + kk * 64 + g * 16) ^ ((row & 7) << 4)));
            }
#pragma unroll
            for (int ni = 0; ni < 4; ++ni) {
                int row = wn * 64 + ni * 16 + c;
                bfr[ni] = *(const bf16x8*)(Bsm + ((row * 128 + kk * 64 + g * 16) ^ ((row & 7) << 4)));
            }
#pragma unroll
            for (int mi = 0; mi < 4; ++mi)
#pragma unroll
                for (int ni = 0; ni < 4; ++ni)
                    acc[mi][ni] = __builtin_amdgcn_mfma_f32_16x16x32_bf16(
                        af[mi], bfr[ni], acc[mi][ni], 0, 0, 0);
        }
    }

#pragma unroll
    for (int ni = 0; ni < 4; ++ni) {
        int n = bn + wn * 64 + ni * 16 + c;
#pragma unroll
        for (int mi = 0; mi < 4; ++mi)
#pragma unroll
            for (int r = 0; r < 4; ++r) {
                int m = bm + wm * 64 + mi * 16 + g * 4 + r;
                out[(size_t)m * DM + n] = acc[mi][ni][r];
            }
    }
}

// ---------------------------------------------------------------------------
extern "C" void kernel_launch(void* const* d_in, const int* in_sizes, int n_in,
                              void* d_out, int out_size, void* d_ws, size_t ws_size,
                              hipStream_t stream)
{
    const float* x  = (const float*)d_in[0];
    const float* wq = (const float*)d_in[1];
    const float* wo = (const float*)d_in[2];
    const float* ls = (const float*)d_in[3];
    const float* ll = (const float*)d_in[4];
    float* out = (float*)d_out;

    char* ws = (char*)d_ws;
    size_t off = 0;
    float* cosT  = (float*)(ws + off); off += (size_t)NH * NSEQ * KP * 4;        // 2 MB
    float* sinT  = (float*)(ws + off); off += (size_t)NH * NSEQ * KP * 4;        // 2 MB
    float* biasK = (float*)(ws + off); off += (size_t)NH * NSEQ * 4;             // 64 KB
    unsigned short* xb  = (unsigned short*)(ws + off); off += (size_t)MROWS * DM * 2;      // 4 MB
    unsigned short* wqT = (unsigned short*)(ws + off); off += (size_t)DM * 3 * DM * 2;     // 1.5 MB
    unsigned short* woT = (unsigned short*)(ws + off); off += (size_t)DM * DM * 2;         // 0.5 MB
    unsigned short* qbf = (unsigned short*)(ws + off); off += (size_t)MROWS * DM * 2;      // 4 MB
    unsigned short* kbf = (unsigned short*)(ws + off); off += (size_t)MROWS * DM * 2;      // 4 MB
    unsigned short* vtb = (unsigned short*)(ws + off); off += (size_t)MROWS * DM * 2;      // 4 MB
    unsigned short* aob = (unsigned short*)(ws + off); off += (size_t)MROWS * DM * 2;      // 4 MB
    unsigned short* opart = (unsigned short*)(ws + off);
    off += (size_t)NB * NH * SLOTS * 64 * 64 * 2;                                // 10.5 MB
    float* mlpart = (float*)(ws + off); off += (size_t)NB * NH * SLOTS * 64 * 2 * 4; // 0.66 MB

    k_tables<<<(NH * NSEQ + 255) / 256, 256, 0, stream>>>(ls, ll, cosT, sinT, biasK);
    k_cvt_bf16<<<(MROWS * DM / 8 + 255) / 256, 256, 0, stream>>>(x, xb, MROWS * DM / 8);
    k_transpose_bf16<<<dim3(3 * DM / 32, DM / 32), 256, 0, stream>>>(wq, wqT, DM, 3 * DM);
    k_transpose_bf16<<<dim3(DM / 32, DM / 32), 256, 0, stream>>>(wo, woT, DM, DM);
    k_gemm_qkv<<<dim3(3 * DM / 128, MROWS / 128), 256, 0, stream>>>(
        xb, wqT, cosT, sinT, qbf, kbf, vtb);
    k_attn<<<dim3(SLOTS, NB * NH), 256, 0, stream>>>(
        qbf, kbf, vtb, biasK, aob, opart, mlpart);
    k_merge<<<dim3(24, NB * NH), 256, 0, stream>>>(opart, mlpart, aob);
    k_gemm_out<<<dim3(DM / 128, MROWS / 128), 256, 0, stream>>>(aob, woT, out);
}

// Round 8
// 97.899 us; speedup vs baseline: 6.7963x; 1.0367x over previous
//
#include <hip/hip_runtime.h>
#include <hip/hip_bf16.h>
#include <math.h>

#define NSEQ 2048
#define NH 8
#define DH 64
#define KP 32
#define DM 512
#define NB 2
#define MROWS (NB * NSEQ)   // 4096
#define SLOTS 80            // key-chunk slots per (b,h): sum_{g=0..3} 8*(g+1)

typedef short bf16x8 __attribute__((ext_vector_type(8)));
typedef float f32x4  __attribute__((ext_vector_type(4)));

static __constant__ float RZF[KP] = {
    14.134725142f, 21.022039639f, 25.01085758f,  30.424876126f, 32.935061588f,
    37.586178159f, 40.918719012f, 43.327073281f, 48.005150881f, 49.773832478f,
    52.970321478f, 56.446247697f, 59.347044003f, 60.831778525f, 65.112544048f,
    67.079810529f, 69.546401711f, 72.067157674f, 75.704690699f, 77.144840069f,
    79.33737502f,  82.910380854f, 84.735492981f, 87.425274613f, 88.809111208f,
    92.491899271f, 94.651344041f, 95.870634228f, 98.831194218f, 101.317851006f,
    103.72553804f, 105.446623052f};

static __device__ __forceinline__ unsigned short f2bf(float f) {
    unsigned int u = __float_as_uint(f);
    unsigned int r = (u + 0x7FFFu + ((u >> 16) & 1u)) >> 16;   // RNE
    return (unsigned short)r;
}
static __device__ __forceinline__ float bf2f(unsigned short s) {
    return __uint_as_float((unsigned int)s << 16);
}

// async global->LDS, 16B per lane; LDS dest = wave-uniform base + lane*16
static __device__ __forceinline__ void gload16(const void* g, void* l) {
    __builtin_amdgcn_global_load_lds(
        (const __attribute__((address_space(1))) void*)g,
        (__attribute__((address_space(3))) void*)l, 16, 0, 0);
}

// ---------------------------------------------------------------------------
// K0: fused prep. Block ranges:
//  [0,1024)      : x f32 -> bf16 (8 elem/thread)
//  [1024,1792)   : w_qkv transpose-convert  [512][1536] -> [1536][512] bf16
//  [1792,2048)   : w_o   transpose-convert  [512][512]  -> [512][512]  bf16
//  [2048,2112)   : tables cos/sin/biasK
// ---------------------------------------------------------------------------
__global__ __launch_bounds__(256) void k_prep(
    const float* __restrict__ x, const float* __restrict__ wq,
    const float* __restrict__ wo, const float* __restrict__ ls,
    const float* __restrict__ ll,
    unsigned short* __restrict__ xb, unsigned short* __restrict__ wqT,
    unsigned short* __restrict__ woT,
    float* __restrict__ cosT, float* __restrict__ sinT, float* __restrict__ biasK)
{
    __shared__ float tile[32][33];
    int bid = blockIdx.x;
    int tid = threadIdx.x;
    if (bid < 1024) {
        int i = bid * 256 + tid;            // < 262144 = MROWS*DM/8
        float4 a = ((const float4*)x)[2 * i];
        float4 b = ((const float4*)x)[2 * i + 1];
        union { unsigned short s[8]; uint4 u; } pk;
        pk.s[0] = f2bf(a.x); pk.s[1] = f2bf(a.y); pk.s[2] = f2bf(a.z); pk.s[3] = f2bf(a.w);
        pk.s[4] = f2bf(b.x); pk.s[5] = f2bf(b.y); pk.s[6] = f2bf(b.z); pk.s[7] = f2bf(b.w);
        ((uint4*)xb)[i] = pk.u;
    } else if (bid < 2048) {
        const float* src; unsigned short* dst; int R, C, bx, by;
        if (bid < 1792) { src = wq; dst = wqT; R = DM; C = 3 * DM;
                          int ix = bid - 1024; bx = ix % 48; by = ix / 48; }
        else            { src = wo; dst = woT; R = DM; C = DM;
                          int ix = bid - 1792; bx = ix & 15; by = ix >> 4; }
        int x0 = bx << 5, y0 = by << 5;
        int tx = tid & 31, ty = tid >> 5;
#pragma unroll
        for (int i = 0; i < 4; ++i)
            tile[ty + i * 8][tx] = src[(size_t)(y0 + ty + i * 8) * C + x0 + tx];
        __syncthreads();
#pragma unroll
        for (int i = 0; i < 4; ++i)
            dst[(size_t)(x0 + ty + i * 8) * R + y0 + tx] = f2bf(tile[tx][ty + i * 8]);
    } else {
        int idx = (bid - 2048) * 256 + tid;     // < 16384 = NH*NSEQ
        int h = idx >> 11;
        int t = idx & (NSEQ - 1);
        float scale = expf(ls[h]);
        float lam32 = expf(ll[h]) * (1.0f / 32.0f);
        float tau = log1pf((float)t);
        const float TAUF = 6.2831853071795864769f;
        float ssum = 0.0f;
        float* cp = cosT + (size_t)idx * KP;
        float* sp = sinT + (size_t)idx * KP;
#pragma unroll
        for (int p = 0; p < KP; ++p) {
            float g  = RZF[p] / RZF[0];
            float th = (tau * g) * scale;
            cp[p] = cosf(th);
            sp[p] = sinf(th);
            ssum += floorf(th / TAUF);
        }
        biasK[idx] = lam32 * ssum;
    }
}

// ---------------------------------------------------------------------------
// K2: MFMA GEMM  xb(4096x512 bf16) @ wqT^T, fused rotation epilogue.
// q_rot/k_rot -> [b][h][n][dh] bf16;  V -> TRANSPOSED [b][h][dh][n] bf16.
// ---------------------------------------------------------------------------
__global__ __launch_bounds__(256) void k_gemm_qkv(
    const unsigned short* __restrict__ xb, const unsigned short* __restrict__ wt,
    const float* __restrict__ cosT, const float* __restrict__ sinT,
    unsigned short* __restrict__ qrot, unsigned short* __restrict__ krot,
    unsigned short* __restrict__ vtout)
{
    __shared__ char Asm[128 * 128];   // 128 rows x 128B (64 bf16), swizzled
    __shared__ char Bsm[128 * 128];
    int tid = threadIdx.x;
    int w = tid >> 6, lane = tid & 63, g = lane >> 4, c = lane & 15;
    int wm = w >> 1, wn = w & 1;
    int bm = blockIdx.y << 7, bn = blockIdx.x << 7;
    int rin = lane >> 3;                       // row-in-8-row-chunk
    int csw = ((lane & 7) ^ rin) << 4;         // pre-swizzled source byte-col

    f32x4 acc[4][4];
#pragma unroll
    for (int mi = 0; mi < 4; ++mi)
#pragma unroll
        for (int ni = 0; ni < 4; ++ni) acc[mi][ni] = (f32x4){0.f, 0.f, 0.f, 0.f};

    const char* Ag = (const char*)xb;
    const char* Bg = (const char*)wt;

    for (int k0 = 0; k0 < DM; k0 += 64) {
        __syncthreads();
#pragma unroll
        for (int ch = 0; ch < 4; ++ch) {
            int row = (w * 4 + ch) * 8 + rin;
            gload16(Ag + ((size_t)(bm + row) * DM + k0) * 2 + csw, Asm + (w * 4 + ch) * 1024);
            gload16(Bg + ((size_t)(bn + row) * DM + k0) * 2 + csw, Bsm + (w * 4 + ch) * 1024);
        }
        asm volatile("s_waitcnt vmcnt(0)" ::: "memory");
        __syncthreads();
#pragma unroll
        for (int kk = 0; kk < 2; ++kk) {
            bf16x8 af[4], bfr[4];
#pragma unroll
            for (int mi = 0; mi < 4; ++mi) {
                int row = wm * 64 + mi * 16 + c;
                af[mi] = *(const bf16x8*)(Asm + ((row * 128 + kk * 64 + g * 16) ^ ((row & 7) << 4)));
            }
#pragma unroll
            for (int ni = 0; ni < 4; ++ni) {
                int row = wn * 64 + ni * 16 + c;
                bfr[ni] = *(const bf16x8*)(Bsm + ((row * 128 + kk * 64 + g * 16) ^ ((row & 7) << 4)));
            }
#pragma unroll
            for (int mi = 0; mi < 4; ++mi)
#pragma unroll
                for (int ni = 0; ni < 4; ++ni)
                    acc[mi][ni] = __builtin_amdgcn_mfma_f32_16x16x32_bf16(
                        af[mi], bfr[ni], acc[mi][ni], 0, 0, 0);
        }
    }

    // epilogue: lane holds C[m = ..+g*4+r][n = ..+c] (wave-uniform section)
    int lane_odd = c & 1;
#pragma unroll
    for (int ni = 0; ni < 4; ++ni) {
        int n = bn + wn * 64 + ni * 16 + c;
        int sec = n >> 9;               // 0=q 1=k 2=v
        int dmod = n & 511;
        int h = dmod >> 6, dh = dmod & 63, p = dh >> 1;
        if (sec == 2) {
            // V^T: vt[(b*8+h)*64 + dh][t] ; pack 4 consecutive t per 8B store
#pragma unroll
            for (int mi = 0; mi < 4; ++mi) {
                int m0 = bm + wm * 64 + mi * 16 + g * 4;
                int b = m0 >> 11, t0 = m0 & (NSEQ - 1);
                union { unsigned short s[4]; uint2 u; } pk;
                pk.s[0] = f2bf(acc[mi][ni][0]); pk.s[1] = f2bf(acc[mi][ni][1]);
                pk.s[2] = f2bf(acc[mi][ni][2]); pk.s[3] = f2bf(acc[mi][ni][3]);
                *(uint2*)(vtout + ((size_t)(b * NH + h) * DH + dh) * NSEQ + t0) = pk.u;
            }
        } else {
            const float* cb_ = cosT + (size_t)h * NSEQ * KP + p;
            const float* sb_ = sinT + (size_t)h * NSEQ * KP + p;
            unsigned short* dst = (sec == 0) ? qrot : krot;
#pragma unroll
            for (int mi = 0; mi < 4; ++mi) {
#pragma unroll
                for (int r = 0; r < 4; ++r) {
                    int m = bm + wm * 64 + mi * 16 + g * 4 + r;
                    int b = m >> 11, t = m & (NSEQ - 1);
                    float val = acc[mi][ni][r];
                    float pv = __shfl_xor(val, 1);
                    float cv = cb_[(size_t)t * KP], sv = sb_[(size_t)t * KP];
                    float o = lane_odd ? (pv * sv + val * cv) : (val * cv - pv * sv);
                    dst[((size_t)(b * NH + h) * NSEQ + t) * DH + dh] = f2bf(o);
                }
            }
        }
    }
}

// ---------------------------------------------------------------------------
// K3: split-K MFMA flash attention, phase 1. Grid (SLOTS=80, 16 bh).
// Double-buffered K/V^T staging via global_load_lds with pre-swizzled source,
// issue-early (stage j+1 before compute j, r6-proven), explicit vmcnt(0)
// drain before each barrier; defer-max (T13).
// ---------------------------------------------------------------------------
__global__ __launch_bounds__(256) void k_attn(
    const unsigned short* __restrict__ qr, const unsigned short* __restrict__ kr,
    const unsigned short* __restrict__ vt, const float* __restrict__ biasK,
    unsigned short* __restrict__ ao, unsigned short* __restrict__ opart,
    float* __restrict__ mlpart)
{
    __shared__ char Kbuf[2][8192];              // [key][dh] bf16, row-swizzled
    __shared__ char Vbuf[2][8192];              // [d][key]  bf16, row-swizzled
    __shared__ __hip_bfloat16 Pl[4][16 * 64];   // per-wave [q][key], row-swizzled
    __shared__ float Bk[2][64];

    int bh = blockIdx.y;            // b*8 + h
    int b = bh >> 3, h = bh & 7;
    // decode slot -> (qt, ci)
    int s = blockIdx.x;
    int g4 = 0, base = 0;
    while (s >= base + 8 * (g4 + 1)) { base += 8 * (g4 + 1); ++g4; }
    int rem = s - base;
    int qt = g4 * 8 + rem / (g4 + 1);
    int ci = rem % (g4 + 1);
    int nch = (qt >> 3) + 1;
    int t0 = ci * 8;
    int t1 = min(t0 + 8, qt + 1);

    int q0 = qt << 6;
    int tid = threadIdx.x;
    int w    = tid >> 6;
    int lane = tid & 63;
    int g    = lane >> 4;
    int c    = lane & 15;
    char* Pb = (char*)(&Pl[w][0]);

    const char* kb  = (const char*)(kr + (size_t)bh * NSEQ * DH);
    const char* vtb = (const char*)(vt + (size_t)bh * DH * NSEQ);
    const unsigned short* qb = qr + (size_t)bh * NSEQ * DH;
    const float* bkrow = biasK + (size_t)h * NSEQ;

    int qg = q0 + (w << 4) + c;     // this lane's softmax row (q = c)

    // Q fragments (B-operand of swapped QK^T)
    bf16x8 qf[2];
#pragma unroll
    for (int sl = 0; sl < 2; ++sl)
        qf[sl] = *(const bf16x8*)(qb + (size_t)qg * DH + sl * 32 + g * 8);

    f32x4 oa[4];
#pragma unroll
    for (int dt = 0; dt < 4; ++dt) oa[dt] = (f32x4){0.f, 0.f, 0.f, 0.f};
    float mr = -3.0e38f, lr = 0.0f;

    int rin = lane >> 3;
    int swz = ((lane & 7) ^ rin) << 4;          // pre-swizzled source byte-col

    // stage one 64-key tile into buffer: wave w does K/V chunks 2w,2w+1
    auto stage = [&](int buf, int j0) {
#pragma unroll
        for (int i = 0; i < 2; ++i) {
            int ch = w * 2 + i;
            int row = ch * 8 + rin;
            gload16(kb  + (size_t)(j0 + row) * 128 + swz, Kbuf[buf] + ch * 1024);
            gload16(vtb + (size_t)row * (NSEQ * 2) + (size_t)j0 * 2 + swz,
                    Vbuf[buf] + ch * 1024);
        }
        if (tid < 64) Bk[buf][tid] = bkrow[j0 + tid];
    };

    stage(0, t0 << 6);
    asm volatile("s_waitcnt vmcnt(0)" ::: "memory");
    __syncthreads();
    int cur = 0;

    for (int tile = t0; tile < t1; ++tile) {
        int j0 = tile << 6;
        if (tile + 1 < t1) stage(cur ^ 1, j0 + 64);    // issue-early (T14)

        // ---- S^T = K · Q^T ----
        f32x4 st[4];
#pragma unroll
        for (int kt = 0; kt < 4; ++kt) st[kt] = (f32x4){0.f, 0.f, 0.f, 0.f};
#pragma unroll
        for (int sl = 0; sl < 2; ++sl) {
#pragma unroll
            for (int kt = 0; kt < 4; ++kt) {
                int row = kt * 16 + c;
                bf16x8 af = *(const bf16x8*)(Kbuf[cur] +
                    ((row * 128 + sl * 64 + g * 16) ^ ((row & 7) << 4)));
                st[kt] = __builtin_amdgcn_mfma_f32_16x16x32_bf16(af, qf[sl], st[kt], 0, 0, 0);
            }
        }

        // ---- bias + causal mask; lane owns S^T[key=kt*16+g*4+r4][q=c] ----
        bool diagT = (tile == qt);
        float sv[16];
#pragma unroll
        for (int kt = 0; kt < 4; ++kt) {
#pragma unroll
            for (int r4 = 0; r4 < 4; ++r4) {
                int ki = kt * 16 + g * 4 + r4;
                float vl = st[kt][r4] * 0.125f + Bk[cur][ki];
                if (diagT && (j0 + ki > qg)) vl = -3.0e38f;
                sv[kt * 4 + r4] = vl;
            }
        }

        // ---- online softmax with defer-max (T13) ----
        float m16 = sv[0];
#pragma unroll
        for (int i = 1; i < 16; ++i) m16 = fmaxf(m16, sv[i]);
        m16 = fmaxf(m16, __shfl_xor(m16, 16));
        m16 = fmaxf(m16, __shfl_xor(m16, 32));
        if (__any(m16 > mr + 8.0f)) {
            float mt = fmaxf(mr, m16);
            float corr = __expf(mr - mt);
            mr = mt;
            lr *= corr;
            float corrO[4];
#pragma unroll
            for (int r4 = 0; r4 < 4; ++r4) corrO[r4] = __shfl(corr, g * 4 + r4);
#pragma unroll
            for (int dt = 0; dt < 4; ++dt)
#pragma unroll
                for (int r4 = 0; r4 < 4; ++r4) oa[dt][r4] *= corrO[r4];
        }
        float psum = 0.0f;
        unsigned int pw[8];
#pragma unroll
        for (int i = 0; i < 8; ++i) {
            float p0 = __expf(sv[2 * i]     - mr);
            float p1 = __expf(sv[2 * i + 1] - mr);
            psum += p0 + p1;
            pw[i] = (unsigned int)f2bf(p0) | ((unsigned int)f2bf(p1) << 16);
        }
        lr += psum;

        // ---- P (bf16) -> per-wave LDS: [q=c][key] ----
#pragma unroll
        for (int kt = 0; kt < 4; ++kt) {
            uint2 u2; u2.x = pw[2 * kt]; u2.y = pw[2 * kt + 1];
            *(uint2*)(Pb + ((c * 128 + kt * 32 + g * 8) ^ ((c & 7) << 4))) = u2;
        }

        // ---- O += P · V ----
#pragma unroll
        for (int sl = 0; sl < 2; ++sl) {
            bf16x8 pa = *(const bf16x8*)(Pb + ((c * 128 + sl * 64 + g * 16) ^ ((c & 7) << 4)));
#pragma unroll
            for (int dt = 0; dt < 4; ++dt) {
                int d = dt * 16 + c;
                bf16x8 vf = *(const bf16x8*)(Vbuf[cur] +
                    ((d * 128 + sl * 64 + g * 16) ^ ((d & 7) << 4)));
                oa[dt] = __builtin_amdgcn_mfma_f32_16x16x32_bf16(pa, vf, oa[dt], 0, 0, 0);
            }
        }
        asm volatile("s_waitcnt vmcnt(0)" ::: "memory");   // drain next-tile DMA
        __syncthreads();
        cur ^= 1;
    }

    // ---- epilogue: reduce l across groups; lane holds O[q=g*4+r4][d=dt*16+c]
    lr += __shfl_xor(lr, 16);
    lr += __shfl_xor(lr, 32);
    if (nch == 1) {
        float inv = 1.0f / lr;
        float invO[4];
#pragma unroll
        for (int r4 = 0; r4 < 4; ++r4) invO[r4] = __shfl(inv, g * 4 + r4);
#pragma unroll
        for (int dt = 0; dt < 4; ++dt)
#pragma unroll
            for (int r4 = 0; r4 < 4; ++r4) {
                int row = q0 + (w << 4) + g * 4 + r4;
                ao[((size_t)b * NSEQ + row) * DM + h * DH + dt * 16 + c] =
                    f2bf(oa[dt][r4] * invO[r4]);
            }
    } else {
        size_t obase = ((size_t)bh * SLOTS + blockIdx.x) * (64 * 64);
#pragma unroll
        for (int dt = 0; dt < 4; ++dt)
#pragma unroll
            for (int r4 = 0; r4 < 4; ++r4) {
                int row = (w << 4) + g * 4 + r4;     // row within block
                opart[obase + row * 64 + dt * 16 + c] = f2bf(oa[dt][r4]);
            }
        if (g == 0) {   // one lane-group per row writes (m, l); row = w*16 + c
            size_t mb = (((size_t)bh * SLOTS + blockIdx.x) * 64 + (w << 4) + c) * 2;
            mlpart[mb]     = mr;
            mlpart[mb + 1] = lr;
        }
    }
}

// ---------------------------------------------------------------------------
// K3b: phase-2 merge for qt >= 8 (2..4 chunks). Grid (24, 16bh), 256 thr.
// ---------------------------------------------------------------------------
__global__ __launch_bounds__(256) void k_merge(
    const unsigned short* __restrict__ opart, const float* __restrict__ mlpart,
    unsigned short* __restrict__ ao)
{
    int bh = blockIdx.y;
    int b = bh >> 3, h = bh & 7;
    int qt = 8 + blockIdx.x;              // 8..31
    int g4 = qt >> 3;                     // 1..3
    int nch = g4 + 1;
    int slot0 = 4 * g4 * (g4 + 1) + (qt - 8 * g4) * (g4 + 1);
    int tid = threadIdx.x;
    int row = tid >> 2;
    int d0 = (tid & 3) << 4;

    size_t pbase = ((size_t)bh * SLOTS + slot0) * 4096 + row * 64 + d0;
    size_t mbase = (((size_t)bh * SLOTS + slot0) * 64 + row) * 2;

    float M = -3.0e38f;
#pragma unroll
    for (int cc = 0; cc < 4; ++cc)
        if (cc < nch) M = fmaxf(M, mlpart[mbase + (size_t)cc * 128]);

    float L = 0.0f;
    float o[16];
#pragma unroll
    for (int i = 0; i < 16; ++i) o[i] = 0.0f;
#pragma unroll
    for (int cc = 0; cc < 4; ++cc) {
        if (cc < nch) {
            float mc = mlpart[mbase + (size_t)cc * 128];
            float lc = mlpart[mbase + (size_t)cc * 128 + 1];
            float wgt = __expf(mc - M);
            L += lc * wgt;
            union { uint4 u; unsigned short sh[8]; } lo, hi;
            lo.u = *(const uint4*)(opart + pbase + (size_t)cc * 4096);
            hi.u = *(const uint4*)(opart + pbase + (size_t)cc * 4096 + 8);
#pragma unroll
            for (int i = 0; i < 8; ++i) {
                o[i]     += bf2f(lo.sh[i]) * wgt;
                o[i + 8] += bf2f(hi.sh[i]) * wgt;
            }
        }
    }
    float invL = 1.0f / L;
    int grow = (qt << 6) + row;
    unsigned short* dst = ao + ((size_t)b * NSEQ + grow) * DM + h * DH + d0;
    union { unsigned short sh[8]; uint4 u; } p0, p1;
#pragma unroll
    for (int i = 0; i < 8; ++i) {
        p0.sh[i] = f2bf(o[i] * invL);
        p1.sh[i] = f2bf(o[i + 8] * invL);
    }
    *(uint4*)dst = p0.u;
    *(uint4*)(dst + 8) = p1.u;
}

// ---------------------------------------------------------------------------
// K4: MFMA GEMM  aob(4096x512 bf16) @ woT^T -> f32 out.
// BM=64, BN=128 -> grid (4, 64) = 256 blocks = 1/CU exactly (was 128 blocks
// = half the GPU idle). Waves 2x2, each 32x64 (2x4 16x16 tiles).
// ---------------------------------------------------------------------------
__global__ __launch_bounds__(256) void k_gemm_out(
    const unsigned short* __restrict__ aob, const unsigned short* __restrict__ wt,
    float* __restrict__ out)
{
    __shared__ char Asm[64 * 128];    // 8 KB
    __shared__ char Bsm[128 * 128];   // 16 KB
    int tid = threadIdx.x;
    int w = tid >> 6, lane = tid & 63, g = lane >> 4, c = lane & 15;
    int wm = w >> 1, wn = w & 1;
    int bm = blockIdx.y << 6, bn = blockIdx.x << 7;
    int rin = lane >> 3;
    int csw = ((lane & 7) ^ rin) << 4;

    f32x4 acc[2][4];
#pragma unroll
    for (int mi = 0; mi < 2; ++mi)
#pragma unroll
        for (int ni = 0; ni < 4; ++ni) acc[mi][ni] = (f32x4){0.f, 0.f, 0.f, 0.f};

    const char* Ag = (const char*)aob;
    const char* Bg = (const char*)wt;

    for (int k0 = 0; k0 < DM; k0 += 64) {
        __syncthreads();
#pragma unroll
        for (int ch = 0; ch < 2; ++ch) {            // A: 8 chunks (64 rows)
            int chA = w * 2 + ch;
            int row = chA * 8 + rin;
            gload16(Ag + ((size_t)(bm + row) * DM + k0) * 2 + csw, Asm + chA * 1024);
        }
#pragma unroll
        for (int ch = 0; ch < 4; ++ch) {            // B: 16 chunks (128 rows)
            int chB = w * 4 + ch;
            int row = chB * 8 + rin;
            gload16(Bg + ((size_t)(bn + row) * DM + k0) * 2 + csw, Bsm + chB * 1024);
        }
        asm volatile("s_waitcnt vmcnt(0)" ::: "memory");
        __syncthreads();
#pragma unroll
        for (int kk = 0; kk < 2; ++kk) {
            bf16x8 af[2], bfr[4];
#pragma unroll
            for (int mi = 0; mi < 2; ++mi) {
                int row = wm * 32 + mi * 16 + c;
                af[mi] = *(const bf16x8*)(Asm + ((row * 128 + kk * 64 + g * 16) ^ ((row & 7) << 4)));
            }
#pragma unroll
            for (int ni = 0; ni < 4; ++ni) {
                int row = wn * 64 + ni * 16 + c;
                bfr[ni] = *(const bf16x8*)(Bsm + ((row * 128 + kk * 64 + g * 16) ^ ((row & 7) << 4)));
            }
#pragma unroll
            for (int mi = 0; mi < 2; ++mi)
#pragma unroll
                for (int ni = 0; ni < 4; ++ni)
                    acc[mi][ni] = __builtin_amdgcn_mfma_f32_16x16x32_bf16(
                        af[mi], bfr[ni], acc[mi][ni], 0, 0, 0);
        }
    }

#pragma unroll
    for (int ni = 0; ni < 4; ++ni) {
        int n = bn + wn * 64 + ni * 16 + c;
#pragma unroll
        for (int mi = 0; mi < 2; ++mi)
#pragma unroll
            for (int r = 0; r < 4; ++r) {
                int m = bm + wm * 32 + mi * 16 + g * 4 + r;
                out[(size_t)m * DM + n] = acc[mi][ni][r];
            }
    }
}

// ---------------------------------------------------------------------------
extern "C" void kernel_launch(void* const* d_in, const int* in_sizes, int n_in,
                              void* d_out, int out_size, void* d_ws, size_t ws_size,
                              hipStream_t stream)
{
    const float* x  = (const float*)d_in[0];
    const float* wq = (const float*)d_in[1];
    const float* wo = (const float*)d_in[2];
    const float* ls = (const float*)d_in[3];
    const float* ll = (const float*)d_in[4];
    float* out = (float*)d_out;

    char* ws = (char*)d_ws;
    size_t off = 0;
    float* cosT  = (float*)(ws + off); off += (size_t)NH * NSEQ * KP * 4;        // 2 MB
    float* sinT  = (float*)(ws + off); off += (size_t)NH * NSEQ * KP * 4;        // 2 MB
    float* biasK = (float*)(ws + off); off += (size_t)NH * NSEQ * 4;             // 64 KB
    unsigned short* xb  = (unsigned short*)(ws + off); off += (size_t)MROWS * DM * 2;      // 4 MB
    unsigned short* wqT = (unsigned short*)(ws + off); off += (size_t)DM * 3 * DM * 2;     // 1.5 MB
    unsigned short* woT = (unsigned short*)(ws + off); off += (size_t)DM * DM * 2;         // 0.5 MB
    unsigned short* qbf = (unsigned short*)(ws + off); off += (size_t)MROWS * DM * 2;      // 4 MB
    unsigned short* kbf = (unsigned short*)(ws + off); off += (size_t)MROWS * DM * 2;      // 4 MB
    unsigned short* vtb = (unsigned short*)(ws + off); off += (size_t)MROWS * DM * 2;      // 4 MB
    unsigned short* aob = (unsigned short*)(ws + off); off += (size_t)MROWS * DM * 2;      // 4 MB
    unsigned short* opart = (unsigned short*)(ws + off);
    off += (size_t)NB * NH * SLOTS * 64 * 64 * 2;                                // 10.5 MB
    float* mlpart = (float*)(ws + off); off += (size_t)NB * NH * SLOTS * 64 * 2 * 4; // 0.66 MB

    k_prep<<<2112, 256, 0, stream>>>(x, wq, wo, ls, ll, xb, wqT, woT, cosT, sinT, biasK);
    k_gemm_qkv<<<dim3(3 * DM / 128, MROWS / 128), 256, 0, stream>>>(
        xb, wqT, cosT, sinT, qbf, kbf, vtb);
    k_attn<<<dim3(SLOTS, NB * NH), 256, 0, stream>>>(
        qbf, kbf, vtb, biasK, aob, opart, mlpart);
    k_merge<<<dim3(24, NB * NH), 256, 0, stream>>>(opart, mlpart, aob);
    k_gemm_out<<<dim3(DM / 128, MROWS / 64), 256, 0, stream>>>(aob, woT, out);
}

// Round 9
// 95.753 us; speedup vs baseline: 6.9486x; 1.0224x over previous
//
#include <hip/hip_runtime.h>
#include <hip/hip_bf16.h>
#include <math.h>

#define NSEQ 2048
#define NH 8
#define DH 64
#define KP 32
#define DM 512
#define NB 2
#define MROWS (NB * NSEQ)   // 4096
#define SLOT2 40            // key-chunk slots per (b,h) at QBLK=128

typedef short bf16x8 __attribute__((ext_vector_type(8)));
typedef float f32x4  __attribute__((ext_vector_type(4)));

static __constant__ float RZF[KP] = {
    14.134725142f, 21.022039639f, 25.01085758f,  30.424876126f, 32.935061588f,
    37.586178159f, 40.918719012f, 43.327073281f, 48.005150881f, 49.773832478f,
    52.970321478f, 56.446247697f, 59.347044003f, 60.831778525f, 65.112544048f,
    67.079810529f, 69.546401711f, 72.067157674f, 75.704690699f, 77.144840069f,
    79.33737502f,  82.910380854f, 84.735492981f, 87.425274613f, 88.809111208f,
    92.491899271f, 94.651344041f, 95.870634228f, 98.831194218f, 101.317851006f,
    103.72553804f, 105.446623052f};

static __device__ __forceinline__ unsigned short f2bf(float f) {
    unsigned int u = __float_as_uint(f);
    unsigned int r = (u + 0x7FFFu + ((u >> 16) & 1u)) >> 16;   // RNE
    return (unsigned short)r;
}
static __device__ __forceinline__ float bf2f(unsigned short s) {
    return __uint_as_float((unsigned int)s << 16);
}

// async global->LDS, 16B per lane; LDS dest = wave-uniform base + lane*16
static __device__ __forceinline__ void gload16(const void* g, void* l) {
    __builtin_amdgcn_global_load_lds(
        (const __attribute__((address_space(1))) void*)g,
        (__attribute__((address_space(3))) void*)l, 16, 0, 0);
}

// ---------------------------------------------------------------------------
// K0: fused prep (x->bf16, w transposes, tables). Block-range dispatch.
// ---------------------------------------------------------------------------
__global__ __launch_bounds__(256) void k_prep(
    const float* __restrict__ x, const float* __restrict__ wq,
    const float* __restrict__ wo, const float* __restrict__ ls,
    const float* __restrict__ ll,
    unsigned short* __restrict__ xb, unsigned short* __restrict__ wqT,
    unsigned short* __restrict__ woT,
    float* __restrict__ cosT, float* __restrict__ sinT, float* __restrict__ biasK)
{
    __shared__ float tile[32][33];
    int bid = blockIdx.x;
    int tid = threadIdx.x;
    if (bid < 1024) {
        int i = bid * 256 + tid;
        float4 a = ((const float4*)x)[2 * i];
        float4 b = ((const float4*)x)[2 * i + 1];
        union { unsigned short s[8]; uint4 u; } pk;
        pk.s[0] = f2bf(a.x); pk.s[1] = f2bf(a.y); pk.s[2] = f2bf(a.z); pk.s[3] = f2bf(a.w);
        pk.s[4] = f2bf(b.x); pk.s[5] = f2bf(b.y); pk.s[6] = f2bf(b.z); pk.s[7] = f2bf(b.w);
        ((uint4*)xb)[i] = pk.u;
    } else if (bid < 2048) {
        const float* src; unsigned short* dst; int R, C, bx, by;
        if (bid < 1792) { src = wq; dst = wqT; R = DM; C = 3 * DM;
                          int ix = bid - 1024; bx = ix % 48; by = ix / 48; }
        else            { src = wo; dst = woT; R = DM; C = DM;
                          int ix = bid - 1792; bx = ix & 15; by = ix >> 4; }
        int x0 = bx << 5, y0 = by << 5;
        int tx = tid & 31, ty = tid >> 5;
#pragma unroll
        for (int i = 0; i < 4; ++i)
            tile[ty + i * 8][tx] = src[(size_t)(y0 + ty + i * 8) * C + x0 + tx];
        __syncthreads();
#pragma unroll
        for (int i = 0; i < 4; ++i)
            dst[(size_t)(x0 + ty + i * 8) * R + y0 + tx] = f2bf(tile[tx][ty + i * 8]);
    } else {
        int idx = (bid - 2048) * 256 + tid;     // < 16384 = NH*NSEQ
        int h = idx >> 11;
        int t = idx & (NSEQ - 1);
        float scale = expf(ls[h]);
        float lam32 = expf(ll[h]) * (1.0f / 32.0f);
        float tau = log1pf((float)t);
        const float TAUF = 6.2831853071795864769f;
        float ssum = 0.0f;
        float* cp = cosT + (size_t)idx * KP;
        float* sp = sinT + (size_t)idx * KP;
#pragma unroll
        for (int p = 0; p < KP; ++p) {
            float g  = RZF[p] / RZF[0];
            float th = (tau * g) * scale;
            cp[p] = cosf(th);
            sp[p] = sinf(th);
            ssum += floorf(th / TAUF);
        }
        biasK[idx] = lam32 * ssum;
    }
}

// ---------------------------------------------------------------------------
// K2: MFMA GEMM  xb(4096x512 bf16) @ wqT^T, fused rotation epilogue.
// BM=64, BN=128 -> grid (12,64) = 768 blocks = 3/CU (was 384 = 1.5/CU tail).
// q_rot/k_rot -> [b][h][n][dh] bf16;  V -> TRANSPOSED [b][h][dh][n] bf16.
// ---------------------------------------------------------------------------
__global__ __launch_bounds__(256) void k_gemm_qkv(
    const unsigned short* __restrict__ xb, const unsigned short* __restrict__ wt,
    const float* __restrict__ cosT, const float* __restrict__ sinT,
    unsigned short* __restrict__ qrot, unsigned short* __restrict__ krot,
    unsigned short* __restrict__ vtout)
{
    __shared__ char Asm[64 * 128];    // 8 KB
    __shared__ char Bsm[128 * 128];   // 16 KB
    int tid = threadIdx.x;
    int w = tid >> 6, lane = tid & 63, g = lane >> 4, c = lane & 15;
    int wm = w >> 1, wn = w & 1;
    int bm = blockIdx.y << 6, bn = blockIdx.x << 7;
    int rin = lane >> 3;
    int csw = ((lane & 7) ^ rin) << 4;

    f32x4 acc[2][4];
#pragma unroll
    for (int mi = 0; mi < 2; ++mi)
#pragma unroll
        for (int ni = 0; ni < 4; ++ni) acc[mi][ni] = (f32x4){0.f, 0.f, 0.f, 0.f};

    const char* Ag = (const char*)xb;
    const char* Bg = (const char*)wt;

    for (int k0 = 0; k0 < DM; k0 += 64) {
        __syncthreads();
#pragma unroll
        for (int ch = 0; ch < 2; ++ch) {            // A: 8 chunks (64 rows)
            int chA = w * 2 + ch;
            int row = chA * 8 + rin;
            gload16(Ag + ((size_t)(bm + row) * DM + k0) * 2 + csw, Asm + chA * 1024);
        }
#pragma unroll
        for (int ch = 0; ch < 4; ++ch) {            // B: 16 chunks (128 rows)
            int chB = w * 4 + ch;
            int row = chB * 8 + rin;
            gload16(Bg + ((size_t)(bn + row) * DM + k0) * 2 + csw, Bsm + chB * 1024);
        }
        asm volatile("s_waitcnt vmcnt(0)" ::: "memory");
        __syncthreads();
#pragma unroll
        for (int kk = 0; kk < 2; ++kk) {
            bf16x8 af[2], bfr[4];
#pragma unroll
            for (int mi = 0; mi < 2; ++mi) {
                int row = wm * 32 + mi * 16 + c;
                af[mi] = *(const bf16x8*)(Asm + ((row * 128 + kk * 64 + g * 16) ^ ((row & 7) << 4)));
            }
#pragma unroll
            for (int ni = 0; ni < 4; ++ni) {
                int row = wn * 64 + ni * 16 + c;
                bfr[ni] = *(const bf16x8*)(Bsm + ((row * 128 + kk * 64 + g * 16) ^ ((row & 7) << 4)));
            }
#pragma unroll
            for (int mi = 0; mi < 2; ++mi)
#pragma unroll
                for (int ni = 0; ni < 4; ++ni)
                    acc[mi][ni] = __builtin_amdgcn_mfma_f32_16x16x32_bf16(
                        af[mi], bfr[ni], acc[mi][ni], 0, 0, 0);
        }
    }

    // epilogue: lane holds C[m = bm+wm*32+mi*16+g*4+r][n = bn+wn*64+ni*16+c]
    int lane_odd = c & 1;
#pragma unroll
    for (int ni = 0; ni < 4; ++ni) {
        int n = bn + wn * 64 + ni * 16 + c;
        int sec = n >> 9;               // 0=q 1=k 2=v
        int dmod = n & 511;
        int h = dmod >> 6, dh = dmod & 63, p = dh >> 1;
        if (sec == 2) {
#pragma unroll
            for (int mi = 0; mi < 2; ++mi) {
                int m0 = bm + wm * 32 + mi * 16 + g * 4;
                int b = m0 >> 11, t0 = m0 & (NSEQ - 1);
                union { unsigned short s[4]; uint2 u; } pk;
                pk.s[0] = f2bf(acc[mi][ni][0]); pk.s[1] = f2bf(acc[mi][ni][1]);
                pk.s[2] = f2bf(acc[mi][ni][2]); pk.s[3] = f2bf(acc[mi][ni][3]);
                *(uint2*)(vtout + ((size_t)(b * NH + h) * DH + dh) * NSEQ + t0) = pk.u;
            }
        } else {
            const float* cb_ = cosT + (size_t)h * NSEQ * KP + p;
            const float* sb_ = sinT + (size_t)h * NSEQ * KP + p;
            unsigned short* dst = (sec == 0) ? qrot : krot;
#pragma unroll
            for (int mi = 0; mi < 2; ++mi) {
#pragma unroll
                for (int r = 0; r < 4; ++r) {
                    int m = bm + wm * 32 + mi * 16 + g * 4 + r;
                    int b = m >> 11, t = m & (NSEQ - 1);
                    float val = acc[mi][ni][r];
                    float pv = __shfl_xor(val, 1);
                    float cv = cb_[(size_t)t * KP], sv = sb_[(size_t)t * KP];
                    float o = lane_odd ? (pv * sv + val * cv) : (val * cv - pv * sv);
                    dst[((size_t)(b * NH + h) * NSEQ + t) * DH + dh] = f2bf(o);
                }
            }
        }
    }
}

// ---------------------------------------------------------------------------
// K3: split-K MFMA flash attention, QBLK=128: each wave owns 32 q-rows as
// TWO 16-row fragments sharing the K/V fragment reads (halves LDS redundancy
// and staging bytes per flop). Grid (SLOT2=40 heavy-first, 16 bh).
// qt = 128-row q-tile (0..15); key range chunked <=8 64-key tiles.
// ---------------------------------------------------------------------------
__global__ __launch_bounds__(256) void k_attn(
    const unsigned short* __restrict__ qr, const unsigned short* __restrict__ kr,
    const unsigned short* __restrict__ vt, const float* __restrict__ biasK,
    unsigned short* __restrict__ ao, unsigned short* __restrict__ opart,
    float* __restrict__ mlpart)
{
    __shared__ char Kbuf[2][8192];              // [key][dh] bf16, row-swizzled
    __shared__ char Vbuf[2][8192];              // [d][key]  bf16, row-swizzled
    __shared__ char Pl[4][4096];                // per-wave [32 q][64 key] bf16, swizzled
    __shared__ float Bk[2][64];

    int bh = blockIdx.y;            // b*8 + h
    int b = bh >> 3, h = bh & 7;
    int slot = (SLOT2 - 1) - blockIdx.x;        // heavy-first
    // decode slot -> (qt, ci): qt has nch(qt) = (2qt+9)>>3 chunks
    int s = slot, qt = 0, nch;
    for (;;) { nch = (2 * qt + 9) >> 3; if (s < nch) break; s -= nch; ++qt; }
    int ci = s;
    int ntl = 2 * qt + 2;           // key tiles attended by this q-tile
    int t0 = ci << 3;
    int t1 = min(t0 + 8, ntl);

    int q0 = qt << 7;
    int tid = threadIdx.x;
    int w    = tid >> 6;
    int lane = tid & 63;
    int g    = lane >> 4;
    int c    = lane & 15;
    char* Pb = Pl[w];

    const char* kb  = (const char*)(kr + (size_t)bh * NSEQ * DH);
    const char* vtb = (const char*)(vt + (size_t)bh * DH * NSEQ);
    const unsigned short* qb = qr + (size_t)bh * NSEQ * DH;
    const float* bkrow = biasK + (size_t)h * NSEQ;

    int qrow[2] = { q0 + (w << 5) + c, q0 + (w << 5) + 16 + c };

    // Q fragments (B-operand of swapped QK^T), 2 per wave
    bf16x8 qf[2][2];
#pragma unroll
    for (int f = 0; f < 2; ++f)
#pragma unroll
        for (int sl = 0; sl < 2; ++sl)
            qf[f][sl] = *(const bf16x8*)(qb + (size_t)qrow[f] * DH + sl * 32 + g * 8);

    f32x4 oa[2][4];
#pragma unroll
    for (int f = 0; f < 2; ++f)
#pragma unroll
        for (int dt = 0; dt < 4; ++dt) oa[f][dt] = (f32x4){0.f, 0.f, 0.f, 0.f};
    float mr[2] = {-3.0e38f, -3.0e38f}, lr[2] = {0.0f, 0.0f};

    int rin = lane >> 3;
    int swz = ((lane & 7) ^ rin) << 4;          // pre-swizzled source byte-col

    auto stage = [&](int buf, int j0) {
#pragma unroll
        for (int i = 0; i < 2; ++i) {
            int ch = w * 2 + i;
            int row = ch * 8 + rin;
            gload16(kb  + (size_t)(j0 + row) * 128 + swz, Kbuf[buf] + ch * 1024);
            gload16(vtb + (size_t)row * (NSEQ * 2) + (size_t)j0 * 2 + swz,
                    Vbuf[buf] + ch * 1024);
        }
        if (tid < 64) Bk[buf][tid] = bkrow[j0 + tid];
    };

    stage(0, t0 << 6);
    asm volatile("s_waitcnt vmcnt(0)" ::: "memory");
    __syncthreads();
    int cur = 0;

    for (int tile = t0; tile < t1; ++tile) {
        int j0 = tile << 6;
        if (tile + 1 < t1) stage(cur ^ 1, j0 + 64);    // issue-early

        // ---- K fragments once, reused by both q-fragments ----
        bf16x8 af[2][4];    // [slice][key-tile]
#pragma unroll
        for (int sl = 0; sl < 2; ++sl)
#pragma unroll
            for (int kt = 0; kt < 4; ++kt) {
                int row = kt * 16 + c;
                af[sl][kt] = *(const bf16x8*)(Kbuf[cur] +
                    ((row * 128 + sl * 64 + g * 16) ^ ((row & 7) << 4)));
            }

        // ---- S^T = K · Q^T for both fragments ----
        f32x4 st[2][4];
#pragma unroll
        for (int f = 0; f < 2; ++f)
#pragma unroll
            for (int kt = 0; kt < 4; ++kt) st[f][kt] = (f32x4){0.f, 0.f, 0.f, 0.f};
#pragma unroll
        for (int sl = 0; sl < 2; ++sl)
#pragma unroll
            for (int kt = 0; kt < 4; ++kt) {
                st[0][kt] = __builtin_amdgcn_mfma_f32_16x16x32_bf16(
                    af[sl][kt], qf[0][sl], st[0][kt], 0, 0, 0);
                st[1][kt] = __builtin_amdgcn_mfma_f32_16x16x32_bf16(
                    af[sl][kt], qf[1][sl], st[1][kt], 0, 0, 0);
            }

        // ---- per-fragment bias+mask, online softmax (defer-max), P store ----
#pragma unroll
        for (int f = 0; f < 2; ++f) {
            bool diagT = (j0 + 64 > q0 + (w << 5) + f * 16);   // wave-uniform
            float sv[16];
#pragma unroll
            for (int kt = 0; kt < 4; ++kt)
#pragma unroll
                for (int r4 = 0; r4 < 4; ++r4) {
                    int ki = kt * 16 + g * 4 + r4;
                    float vl = st[f][kt][r4] * 0.125f + Bk[cur][ki];
                    if (diagT && (j0 + ki > qrow[f])) vl = -3.0e38f;
                    sv[kt * 4 + r4] = vl;
                }
            float m16 = sv[0];
#pragma unroll
            for (int i = 1; i < 16; ++i) m16 = fmaxf(m16, sv[i]);
            m16 = fmaxf(m16, __shfl_xor(m16, 16));
            m16 = fmaxf(m16, __shfl_xor(m16, 32));
            if (__any(m16 > mr[f] + 8.0f)) {
                float mt = fmaxf(mr[f], m16);
                float corr = __expf(mr[f] - mt);
                mr[f] = mt;
                lr[f] *= corr;
                float corrO[4];
#pragma unroll
                for (int r4 = 0; r4 < 4; ++r4) corrO[r4] = __shfl(corr, g * 4 + r4);
#pragma unroll
                for (int dt = 0; dt < 4; ++dt)
#pragma unroll
                    for (int r4 = 0; r4 < 4; ++r4) oa[f][dt][r4] *= corrO[r4];
            }
            float psum = 0.0f;
            unsigned int pw[8];
#pragma unroll
            for (int i = 0; i < 8; ++i) {
                float p0 = __expf(sv[2 * i]     - mr[f]);
                float p1 = __expf(sv[2 * i + 1] - mr[f]);
                psum += p0 + p1;
                pw[i] = (unsigned int)f2bf(p0) | ((unsigned int)f2bf(p1) << 16);
            }
            lr[f] += psum;
            int prow = f * 16 + c;
#pragma unroll
            for (int kt = 0; kt < 4; ++kt) {
                uint2 u2; u2.x = pw[2 * kt]; u2.y = pw[2 * kt + 1];
                *(uint2*)(Pb + ((prow * 128 + kt * 32 + g * 8) ^ ((prow & 7) << 4))) = u2;
            }
        }

        // ---- O += P · V : V fragments read once, reused by both fragments ----
#pragma unroll
        for (int sl = 0; sl < 2; ++sl) {
            bf16x8 pa[2];
#pragma unroll
            for (int f = 0; f < 2; ++f) {
                int prow = f * 16 + c;
                pa[f] = *(const bf16x8*)(Pb +
                    ((prow * 128 + sl * 64 + g * 16) ^ ((prow & 7) << 4)));
            }
#pragma unroll
            for (int dt = 0; dt < 4; ++dt) {
                int d = dt * 16 + c;
                bf16x8 vf = *(const bf16x8*)(Vbuf[cur] +
                    ((d * 128 + sl * 64 + g * 16) ^ ((d & 7) << 4)));
                oa[0][dt] = __builtin_amdgcn_mfma_f32_16x16x32_bf16(pa[0], vf, oa[0][dt], 0, 0, 0);
                oa[1][dt] = __builtin_amdgcn_mfma_f32_16x16x32_bf16(pa[1], vf, oa[1][dt], 0, 0, 0);
            }
        }
        asm volatile("s_waitcnt vmcnt(0)" ::: "memory");   // drain next-tile DMA
        __syncthreads();
        cur ^= 1;
    }

    // ---- epilogue ----
#pragma unroll
    for (int f = 0; f < 2; ++f) {
        lr[f] += __shfl_xor(lr[f], 16);
        lr[f] += __shfl_xor(lr[f], 32);
    }
    if (nch == 1) {     // qt 0..3: single chunk -> final normalized output
#pragma unroll
        for (int f = 0; f < 2; ++f) {
            float inv = 1.0f / lr[f];
            float invO[4];
#pragma unroll
            for (int r4 = 0; r4 < 4; ++r4) invO[r4] = __shfl(inv, g * 4 + r4);
#pragma unroll
            for (int dt = 0; dt < 4; ++dt)
#pragma unroll
                for (int r4 = 0; r4 < 4; ++r4) {
                    int row = q0 + (w << 5) + f * 16 + g * 4 + r4;
                    ao[((size_t)b * NSEQ + row) * DM + h * DH + dt * 16 + c] =
                        f2bf(oa[f][dt][r4] * invO[r4]);
                }
        }
    } else {
        size_t obase = ((size_t)bh * SLOT2 + slot) * (128 * 64);
#pragma unroll
        for (int f = 0; f < 2; ++f)
#pragma unroll
            for (int dt = 0; dt < 4; ++dt)
#pragma unroll
                for (int r4 = 0; r4 < 4; ++r4) {
                    int row = (w << 5) + f * 16 + g * 4 + r4;   // 0..127
                    opart[obase + row * 64 + dt * 16 + c] = f2bf(oa[f][dt][r4]);
                }
        if (g == 0) {
#pragma unroll
            for (int f = 0; f < 2; ++f) {
                size_t mb = (((size_t)bh * SLOT2 + slot) * 128 + (w << 5) + f * 16 + c) * 2;
                mlpart[mb]     = mr[f];
                mlpart[mb + 1] = lr[f];
            }
        }
    }
}

// ---------------------------------------------------------------------------
// K3b: phase-2 merge for qt >= 4 (2..4 chunks). Grid (12, 16bh), 256 thr.
// Thread: row = tid/2 (0..127), d0 = (tid&1)*32; 32 cols each.
// ---------------------------------------------------------------------------
__global__ __launch_bounds__(256) void k_merge(
    const unsigned short* __restrict__ opart, const float* __restrict__ mlpart,
    unsigned short* __restrict__ ao)
{
    int bh = blockIdx.y;
    int b = bh >> 3, h = bh & 7;
    int qt = 4 + blockIdx.x;              // 4..15
    int nch = (2 * qt + 9) >> 3;          // 2..4
    int slot0 = 0;
    for (int q = 0; q < qt; ++q) slot0 += (2 * q + 9) >> 3;
    int tid = threadIdx.x;
    int row = tid >> 1;                   // 0..127
    int d0 = (tid & 1) << 5;              // 0 or 32

    size_t pbase = ((size_t)bh * SLOT2 + slot0) * 8192 + row * 64 + d0;
    size_t mbase = (((size_t)bh * SLOT2 + slot0) * 128 + row) * 2;

    float M = -3.0e38f;
#pragma unroll
    for (int cc = 0; cc < 4; ++cc)
        if (cc < nch) M = fmaxf(M, mlpart[mbase + (size_t)cc * 256]);

    float L = 0.0f;
    float o[32];
#pragma unroll
    for (int i = 0; i < 32; ++i) o[i] = 0.0f;
#pragma unroll
    for (int cc = 0; cc < 4; ++cc) {
        if (cc < nch) {
            float mc = mlpart[mbase + (size_t)cc * 256];
            float lc = mlpart[mbase + (size_t)cc * 256 + 1];
            float wgt = __expf(mc - M);
            L += lc * wgt;
#pragma unroll
            for (int q4 = 0; q4 < 4; ++q4) {
                union { uint4 u; unsigned short sh[8]; } v;
                v.u = *(const uint4*)(opart + pbase + (size_t)cc * 8192 + q4 * 8);
#pragma unroll
                for (int i = 0; i < 8; ++i) o[q4 * 8 + i] += bf2f(v.sh[i]) * wgt;
            }
        }
    }
    float invL = 1.0f / L;
    int grow = (qt << 7) + row;
    unsigned short* dst = ao + ((size_t)b * NSEQ + grow) * DM + h * DH + d0;
#pragma unroll
    for (int q4 = 0; q4 < 4; ++q4) {
        union { unsigned short sh[8]; uint4 u; } p;
#pragma unroll
        for (int i = 0; i < 8; ++i) p.sh[i] = f2bf(o[q4 * 8 + i] * invL);
        *(uint4*)(dst + q4 * 8) = p.u;
    }
}

// ---------------------------------------------------------------------------
// K4: MFMA GEMM  aob(4096x512 bf16) @ woT^T -> f32 out. 256 blocks = 1/CU.
// ---------------------------------------------------------------------------
__global__ __launch_bounds__(256) void k_gemm_out(
    const unsigned short* __restrict__ aob, const unsigned short* __restrict__ wt,
    float* __restrict__ out)
{
    __shared__ char Asm[64 * 128];    // 8 KB
    __shared__ char Bsm[128 * 128];   // 16 KB
    int tid = threadIdx.x;
    int w = tid >> 6, lane = tid & 63, g = lane >> 4, c = lane & 15;
    int wm = w >> 1, wn = w & 1;
    int bm = blockIdx.y << 6, bn = blockIdx.x << 7;
    int rin = lane >> 3;
    int csw = ((lane & 7) ^ rin) << 4;

    f32x4 acc[2][4];
#pragma unroll
    for (int mi = 0; mi < 2; ++mi)
#pragma unroll
        for (int ni = 0; ni < 4; ++ni) acc[mi][ni] = (f32x4){0.f, 0.f, 0.f, 0.f};

    const char* Ag = (const char*)aob;
    const char* Bg = (const char*)wt;

    for (int k0 = 0; k0 < DM; k0 += 64) {
        __syncthreads();
#pragma unroll
        for (int ch = 0; ch < 2; ++ch) {
            int chA = w * 2 + ch;
            int row = chA * 8 + rin;
            gload16(Ag + ((size_t)(bm + row) * DM + k0) * 2 + csw, Asm + chA * 1024);
        }
#pragma unroll
        for (int ch = 0; ch < 4; ++ch) {
            int chB = w * 4 + ch;
            int row = chB * 8 + rin;
            gload16(Bg + ((size_t)(bn + row) * DM + k0) * 2 + csw, Bsm + chB * 1024);
        }
        asm volatile("s_waitcnt vmcnt(0)" ::: "memory");
        __syncthreads();
#pragma unroll
        for (int kk = 0; kk < 2; ++kk) {
            bf16x8 af[2], bfr[4];
#pragma unroll
            for (int mi = 0; mi < 2; ++mi) {
                int row = wm * 32 + mi * 16 + c;
                af[mi] = *(const bf16x8*)(Asm + ((row * 128 + kk * 64 + g * 16) ^ ((row & 7) << 4)));
            }
#pragma unroll
            for (int ni = 0; ni < 4; ++ni) {
                int row = wn * 64 + ni * 16 + c;
                bfr[ni] = *(const bf16x8*)(Bsm + ((row * 128 + kk * 64 + g * 16) ^ ((row & 7) << 4)));
            }
#pragma unroll
            for (int mi = 0; mi < 2; ++mi)
#pragma unroll
                for (int ni = 0; ni < 4; ++ni)
                    acc[mi][ni] = __builtin_amdgcn_mfma_f32_16x16x32_bf16(
                        af[mi], bfr[ni], acc[mi][ni], 0, 0, 0);
        }
    }

#pragma unroll
    for (int ni = 0; ni < 4; ++ni) {
        int n = bn + wn * 64 + ni * 16 + c;
#pragma unroll
        for (int mi = 0; mi < 2; ++mi)
#pragma unroll
            for (int r = 0; r < 4; ++r) {
                int m = bm + wm * 32 + mi * 16 + g * 4 + r;
                out[(size_t)m * DM + n] = acc[mi][ni][r];
            }
    }
}

// ---------------------------------------------------------------------------
extern "C" void kernel_launch(void* const* d_in, const int* in_sizes, int n_in,
                              void* d_out, int out_size, void* d_ws, size_t ws_size,
                              hipStream_t stream)
{
    const float* x  = (const float*)d_in[0];
    const float* wq = (const float*)d_in[1];
    const float* wo = (const float*)d_in[2];
    const float* ls = (const float*)d_in[3];
    const float* ll = (const float*)d_in[4];
    float* out = (float*)d_out;

    char* ws = (char*)d_ws;
    size_t off = 0;
    float* cosT  = (float*)(ws + off); off += (size_t)NH * NSEQ * KP * 4;        // 2 MB
    float* sinT  = (float*)(ws + off); off += (size_t)NH * NSEQ * KP * 4;        // 2 MB
    float* biasK = (float*)(ws + off); off += (size_t)NH * NSEQ * 4;             // 64 KB
    unsigned short* xb  = (unsigned short*)(ws + off); off += (size_t)MROWS * DM * 2;      // 4 MB
    unsigned short* wqT = (unsigned short*)(ws + off); off += (size_t)DM * 3 * DM * 2;     // 1.5 MB
    unsigned short* woT = (unsigned short*)(ws + off); off += (size_t)DM * DM * 2;         // 0.5 MB
    unsigned short* qbf = (unsigned short*)(ws + off); off += (size_t)MROWS * DM * 2;      // 4 MB
    unsigned short* kbf = (unsigned short*)(ws + off); off += (size_t)MROWS * DM * 2;      // 4 MB
    unsigned short* vtb = (unsigned short*)(ws + off); off += (size_t)MROWS * DM * 2;      // 4 MB
    unsigned short* aob = (unsigned short*)(ws + off); off += (size_t)MROWS * DM * 2;      // 4 MB
    unsigned short* opart = (unsigned short*)(ws + off);
    off += (size_t)NB * NH * SLOT2 * 128 * 64 * 2;                               // 10.5 MB
    float* mlpart = (float*)(ws + off); off += (size_t)NB * NH * SLOT2 * 128 * 2 * 4; // 1.3 MB

    k_prep<<<2112, 256, 0, stream>>>(x, wq, wo, ls, ll, xb, wqT, woT, cosT, sinT, biasK);
    k_gemm_qkv<<<dim3(3 * DM / 128, MROWS / 64), 256, 0, stream>>>(
        xb, wqT, cosT, sinT, qbf, kbf, vtb);
    k_attn<<<dim3(SLOT2, NB * NH), 256, 0, stream>>>(
        qbf, kbf, vtb, biasK, aob, opart, mlpart);
    k_merge<<<dim3(12, NB * NH), 256, 0, stream>>>(opart, mlpart, aob);
    k_gemm_out<<<dim3(DM / 128, MROWS / 64), 256, 0, stream>>>(aob, woT, out);
}